// Round 7
// baseline (1314.683 us; speedup 1.0000x reference)
//
#include <hip/hip_runtime.h>
#include <math.h>

#define DNUM 4000
#define TNUM 2000
#define FEAT 256
#define UNITS 200
#define TOPK 10
#define CS_ENT 1024

typedef __attribute__((ext_vector_type(8))) _Float16 half8;
typedef __attribute__((ext_vector_type(4))) float f32x4;
typedef __attribute__((ext_vector_type(4))) unsigned short us4;

enum { ENONE = 0, ERELU = 1, ERELUSC = 2, ESIG = 3 };

typedef unsigned int u32_g __attribute__((address_space(1)));
typedef unsigned int u32_l __attribute__((address_space(3)));

// fp16 split helpers (RNE via hardware cvt)
__device__ __forceinline__ unsigned short f2h(float x) {
    union { _Float16 h; unsigned short u; } v; v.h = (_Float16)x; return v.u;
}
__device__ __forceinline__ float h2f(unsigned short b) {
    union { _Float16 h; unsigned short u; } v; v.u = b; return (float)v.h;
}
__device__ __forceinline__ void ld_lds16(const void* g, void* l) {
    __builtin_amdgcn_global_load_lds((const u32_g*)g, (u32_l*)l, 16, 0, 0);
}

static inline int cdiv(int a, int b) { return (a + b - 1) / b; }

// ---------------- small utility kernels ----------------

__global__ void fill_zero_k(float* __restrict__ p, int n) {
    int i = blockIdx.x * 256 + threadIdx.x;
    if (i < n) p[i] = 0.f;
}

// out[r] = rsqrt(safe(rowsum)); cols must be %4 (4000/2000 are)
__global__ void rowsum_rsqrt_k(const float* __restrict__ A, int cols, float* __restrict__ out) {
    int r = blockIdx.x;
    int tid = threadIdx.x;
    const float* row = A + (size_t)r * cols;
    float s = 0.f;
    for (int j4 = tid * 4; j4 < cols; j4 += 1024) {
        f32x4 x = *(const f32x4*)&row[j4];
        s += x[0] + x[1] + x[2] + x[3];
    }
    __shared__ float red[256];
    red[tid] = s;
    __syncthreads();
    for (int st = 128; st > 0; st >>= 1) {
        if (tid < st) red[tid] += red[tid + st];
        __syncthreads();
    }
    if (tid == 0) {
        float n = red[0];
        out[r] = (n == 0.f) ? 1.f : (1.f / sqrtf(n));
    }
}

__global__ void colsum_partial_k(const float* __restrict__ A, int rows, int cols,
                                 float* __restrict__ out) {
    int j = blockIdx.x * 256 + threadIdx.x;
    if (j >= cols) return;
    int chunk = blockIdx.y, nch = gridDim.y;
    int r0 = (int)((long long)rows * chunk / nch);
    int r1 = (int)((long long)rows * (chunk + 1) / nch);
    float s = 0.f;
    for (int i = r0; i < r1; i++) s += A[(size_t)i * cols + j];
    atomicAdd(&out[j], s);
}

__global__ void rsqrt_safe_k(float* __restrict__ v, int n) {
    int i = blockIdx.x * 256 + threadIdx.x;
    if (i < n) {
        float x = v[i];
        v[i] = (x == 0.f) ? 1.f : (1.f / sqrtf(x));
    }
}

__global__ void copy_rows_k(const float* __restrict__ src, int F,
                            float* __restrict__ dst, int ldc) {
    int i = blockIdx.x;
    for (int f4 = threadIdx.x * 4; f4 < F; f4 += 1024)
        *(f32x4*)&dst[(size_t)i * ldc + f4] = *(const f32x4*)&src[(size_t)i * F + f4];
}

// ---------------- top-k ----------------
// Wave-per-row register top-k: no LDS, no barriers. One 64-lane wave per row,
// 4 rows per 256-thread block. Stable smaller-index-first tie order.
__global__ void topk_wave_k(const float* __restrict__ S, int cols,
                            float* __restrict__ tv, int* __restrict__ ti,
                            float* __restrict__ rd) {
    int wid = threadIdx.x >> 6;
    int lane = threadIdx.x & 63;
    int row = blockIdx.x * 4 + wid;
    const float* srow = S + (size_t)row * cols;
    float lv[TOPK];
    int li[TOPK];
#pragma unroll
    for (int m = 0; m < TOPK; ++m) { lv[m] = -3.0e38f; li[m] = 0x7fffffff; }
    for (int j = lane; j < cols; j += 64) {
        float v = srow[j];
        if (v > lv[TOPK - 1]) {
            lv[TOPK - 1] = v; li[TOPK - 1] = j;
#pragma unroll
            for (int p = TOPK - 1; p >= 1; --p) {
                if (lv[p] > lv[p - 1]) {
                    float tf = lv[p]; lv[p] = lv[p - 1]; lv[p - 1] = tf;
                    int   tn = li[p]; li[p] = li[p - 1]; li[p - 1] = tn;
                }
            }
        }
    }
    float ssum = 0.f;
#pragma unroll
    for (int m = 0; m < TOPK; ++m) {
        float cv = lv[0];
        int   ci = li[0];
#pragma unroll
        for (int d = 1; d < 64; d <<= 1) {
            float ov = __shfl_xor(cv, d);
            int   oi = __shfl_xor(ci, d);
            if (ov > cv || (ov == cv && oi < ci)) { cv = ov; ci = oi; }
        }
        ssum += cv;
        if (lane == m) {
            tv[(size_t)row * TOPK + m] = cv;
            ti[(size_t)row * TOPK + m] = ci;
        }
        if (li[0] == ci) {  // unique owner pops (compile-time-indexed shift)
#pragma unroll
            for (int p = 0; p < TOPK - 1; ++p) { lv[p] = lv[p + 1]; li[p] = li[p + 1]; }
            lv[TOPK - 1] = -3.0e38f; li[TOPK - 1] = 0x7fffffff;
        }
    }
    if (lane == 0) rd[row] = (ssum == 0.f) ? 1.f : (1.f / sqrtf(ssum));
}

// legacy block top-k (fp32 fallback path)
__global__ void topk_k(const float* __restrict__ S, int cols,
                       float* __restrict__ tv, int* __restrict__ ti,
                       float* __restrict__ rd) {
    int row = blockIdx.x;
    int tid = threadIdx.x;
    const float* srow = S + (size_t)row * cols;
    __shared__ float vals[2048];
    __shared__ float redv[256];
    __shared__ int   redi[256];
    __shared__ float selv[TOPK];
    __shared__ int   seli[TOPK];
    for (int j = tid; j < cols; j += 256) vals[j] = srow[j];
    __syncthreads();
    for (int it = 0; it < TOPK; ++it) {
        float bv = -3.0e38f;
        int bi = 0x7fffffff;
        for (int j = tid; j < cols; j += 256) {
            float v = vals[j];
            if (v > bv || (v == bv && j < bi)) { bv = v; bi = j; }
        }
        redv[tid] = bv; redi[tid] = bi;
        __syncthreads();
        for (int st = 128; st > 0; st >>= 1) {
            if (tid < st) {
                float v2 = redv[tid + st]; int i2 = redi[tid + st];
                if (v2 > redv[tid] || (v2 == redv[tid] && i2 < redi[tid])) {
                    redv[tid] = v2; redi[tid] = i2;
                }
            }
            __syncthreads();
        }
        if (tid == 0) {
            selv[it] = redv[0];
            seli[it] = redi[0];
            vals[redi[0]] = -3.0e38f;
        }
        __syncthreads();
    }
    if (tid < TOPK) {
        tv[(size_t)row * TOPK + tid] = selv[tid];
        ti[(size_t)row * TOPK + tid] = seli[tid];
    }
    if (tid == 0) {
        float s = 0.f;
        for (int m = 0; m < TOPK; m++) s += selv[m];
        rd[row] = (s == 0.f) ? 1.f : (1.f / sqrtf(s));
    }
}

// hub-safe column sum: LDS pre-aggregation (depth<=CS_ENT at ~4cy LDS atomics),
// then one global atomic per (block, nonzero t) -> hub depth <= #blocks.
__global__ void colsum_lds_k(const float* __restrict__ tv, const int* __restrict__ ti,
                             float* __restrict__ rt, int n) {
    __shared__ float acc[TNUM];
    int tid = threadIdx.x;
    for (int i = tid; i < TNUM; i += 256) acc[i] = 0.f;
    __syncthreads();
    int base = blockIdx.x * CS_ENT;
    int end = base + CS_ENT;
    if (end > n) end = n;
    for (int g = base + tid; g < end; g += 256)
        atomicAdd(&acc[ti[g]], tv[g]);
    __syncthreads();
    for (int i = tid; i < TNUM; i += 256) {
        float v = acc[i];
        if (v != 0.f) atomicAdd(&rt[i], v);
    }
}

// legacy direct scatter (fp32 fallback path)
__global__ void scatter_colsum_k(const float* __restrict__ tv, const int* __restrict__ ti,
                                 float* __restrict__ nt, int n) {
    int g = blockIdx.x * 256 + threadIdx.x;
    if (g < n) atomicAdd(&nt[ti[g]], tv[g]);
}

__global__ void gather_hdt_k(const float* __restrict__ tv, const int* __restrict__ ti,
                             const float* __restrict__ rt, const float* __restrict__ rd,
                             const float* __restrict__ ht, int F,
                             float* __restrict__ C, int ldc, int coloff) {
    int i = blockIdx.x;
    int tid = threadIdx.x;
    __shared__ float w[TOPK];
    __shared__ int   id[TOPK];
    if (tid < TOPK) {
        int idx = ti[(size_t)i * TOPK + tid];
        id[tid] = idx;
        w[tid] = tv[(size_t)i * TOPK + tid] * rt[idx];
    }
    __syncthreads();
    float s = rd[i];
    for (int f = tid; f < F; f += 256) {
        float acc = 0.f;
#pragma unroll
        for (int m = 0; m < TOPK; ++m)
            acc += w[m] * ht[(size_t)id[m] * F + f];
        C[(size_t)i * ldc + coloff + f] = fmaxf(s * acc, 0.f);
    }
}

// ---------------- dense-R H_td path (persist): place/clear sparse weights in a
// persistent 1-split f16 A-matrix; B reuses the hd K-major pack (PB).
__global__ void place_rp_k(const float* __restrict__ tv, const int* __restrict__ ti,
                           const float* __restrict__ rd, const float* __restrict__ rt,
                           int ldr, float cconst,
                           unsigned short* __restrict__ Rp) {
    int g = blockIdx.x * 256 + threadIdx.x;
    if (g >= DNUM * TOPK) return;
    int d = g / TOPK;
    int t = ti[g];
    float w = tv[g] * rd[d] * rt[t] * cconst;
    Rp[(size_t)t * ldr + d] = f2h(w);
}

__global__ void zero_rp_k(const int* __restrict__ ti, int ldr,
                          unsigned short* __restrict__ Rp) {
    int g = blockIdx.x * 256 + threadIdx.x;
    if (g >= DNUM * TOPK) return;
    int d = g / TOPK;
    int t = ti[g];
    Rp[(size_t)t * ldr + d] = 0;
}

// legacy scatter path (fp32 fallback / non-persist)
__global__ void scatter_htd_k(const float* __restrict__ tv, const int* __restrict__ ti,
                              const float* __restrict__ rd, const float* __restrict__ hd,
                              int F, float* __restrict__ accT) {
    int i = blockIdx.x;
    int tid = threadIdx.x;
    __shared__ float row[256];
    __shared__ float w[TOPK];
    __shared__ int   id[TOPK];
    for (int f = tid; f < F; f += 256) row[f] = hd[(size_t)i * F + f];
    if (tid < TOPK) {
        id[tid] = ti[(size_t)i * TOPK + tid];
        w[tid] = tv[(size_t)i * TOPK + tid] * rd[i];
    }
    __syncthreads();
    for (int m = 0; m < TOPK; ++m) {
        float wm = w[m];
        int j = id[m];
        for (int f = tid; f < F; f += 256)
            atomicAdd(&accT[(size_t)j * F + f], wm * row[f]);
    }
}

__global__ void finalize_htd_k(const float* __restrict__ accT, const float* __restrict__ rt,
                               int F, float* __restrict__ C, int ldc, int coloff) {
    int j = blockIdx.x;
    float s = rt[j];
    for (int f = threadIdx.x; f < F; f += 256)
        C[(size_t)j * ldc + coloff + f] = fmaxf(s * accT[(size_t)j * F + f], 0.f);
}

// ---------------- f16-split pack kernels (vectorized) ----------------
// All Kp, C, ld used here are multiples of 4; bases are 256B-aligned.
// cconst: exact power-of-2 scale so primary AND residual stay f16-normal;
// it is undone via osc in the GEMM epilogue (exact round trip).
__global__ void pack_rows_k(const float* __restrict__ X, int Rtot, int C, int r0,
                            int Kp, int NS, int ld,
                            const float* __restrict__ rs, const float* __restrict__ cs,
                            float cconst,
                            unsigned short* __restrict__ out) {
    int l = blockIdx.x;
    int r = r0 + l;
    unsigned short* orow = out + (size_t)l * ld;
    if (r >= Rtot) {
        us4 z = {0, 0, 0, 0};
        for (int c4 = threadIdx.x * 4; c4 < NS * Kp; c4 += 1024)
            *(us4*)&orow[c4] = z;
        return;
    }
    float rsc = (rs ? rs[r] : 1.f) * cconst;
    const float* xrow = X + (size_t)r * C;
    for (int c4 = threadIdx.x * 4; c4 < Kp; c4 += 1024) {
        float v[4];
        if (c4 + 4 <= C) {
            f32x4 x = *(const f32x4*)&xrow[c4];
            v[0] = x[0]; v[1] = x[1]; v[2] = x[2]; v[3] = x[3];
        } else {
#pragma unroll
            for (int j = 0; j < 4; ++j) v[j] = (c4 + j < C) ? xrow[c4 + j] : 0.f;
        }
        us4 b0v, b1v;
#pragma unroll
        for (int j = 0; j < 4; ++j) {
            float val = v[j] * rsc;
            if (cs && c4 + j < C) val *= cs[c4 + j];
            unsigned short b0 = f2h(val);
            b0v[j] = b0;
            b1v[j] = f2h(val - h2f(b0));
        }
        *(us4*)&orow[c4] = b0v;
        if (NS >= 2) *(us4*)&orow[Kp + c4] = b1v;
    }
}

__global__ void pack_trans_k(const float* __restrict__ X, int Kact, int Ctot, int c0base,
                             int Kp, int NS, int ld,
                             const float* __restrict__ ks, const float* __restrict__ ns,
                             float cconst,
                             unsigned short* __restrict__ out) {
    __shared__ float tile[32][33];
    int c0 = blockIdx.x * 32, k0 = blockIdx.y * 32;
    int ci = threadIdx.x & 31, kq = threadIdx.x >> 5;
    for (int i = 0; i < 4; ++i) {
        int k = k0 + kq * 4 + i;
        int cg = c0base + c0 + ci;
        float v = 0.f;
        if (k < Kact && cg < Ctot) {
            v = X[(size_t)k * Ctot + cg] * cconst;
            if (ks) v *= ks[k];
            if (ns) v *= ns[cg];
        }
        tile[kq * 4 + i][ci] = v;
    }
    __syncthreads();
    // thread (cl, kq) emits 4 consecutive k for one output row c -> ushort4 stores
    int cl = threadIdx.x & 31, kq2 = threadIdx.x >> 5;
    us4 b0v, b1v;
#pragma unroll
    for (int i = 0; i < 4; ++i) {
        float v = tile[kq2 * 4 + i][cl];
        unsigned short b0 = f2h(v);
        b0v[i] = b0;
        b1v[i] = f2h(v - h2f(b0));
    }
    unsigned short* o = out + (size_t)(c0 + cl) * ld + (k0 + kq2 * 4);
    *(us4*)&o[0] = b0v;
    if (NS >= 2) *(us4*)&o[Kp] = b1v;
}

// ---------------- MFMA split-GEMM (XOR-swizzled LDS, conflict-free) ----------------
// Asymmetric splits: A has SA f16 splits, B has SB. Products with i+j<2 only
// (dropped terms <= 2^-22 relative). osc = exact 1/(scaleA*scaleB).
template <int SA, int SB, int EPI>
__global__ __launch_bounds__(256) void gemm_bt_k(
    const unsigned short* __restrict__ A, int ldA,
    const unsigned short* __restrict__ B, int ldB,
    int Kp, int ktot, int splits,
    float* __restrict__ Cpart,
    float* __restrict__ dst, int ldc, int coloff,
    int M, int N, float osc) {
    __shared__ __align__(16) short As[SA][128 * 32];
    __shared__ __align__(16) short Bs[SB][128 * 32];
    int tid = threadIdx.x;
    int lane = tid & 63, wid = tid >> 6;
    int wm = wid >> 1, wn = wid & 1;
    int bm = blockIdx.y * 128, bn = blockIdx.x * 128;
    int z = blockIdx.z;
    int kt0 = (int)((long long)ktot * z / splits);
    int kt1 = (int)((long long)ktot * (z + 1) / splits);
    int r_i = lane & 15, quad = lane >> 4;
    int sw = (quad ^ ((r_i >> 1) & 3)) << 3;
    f32x4 acc[4][4] = {};
    for (int t = kt0; t < kt1; ++t) {
        int kbase = t * 32;
#pragma unroll
        for (int s = 0; s < SA; ++s)
#pragma unroll
            for (int it = 0; it < 2; ++it) {
                int flat = (it * 256 + tid) * 8;
                int row = flat >> 5;
                int blk = (flat >> 3) & 3;
                int ko = ((blk ^ ((row >> 1) & 3)) << 3);
                ld_lds16(A + (size_t)(bm + row) * ldA + s * Kp + kbase + ko, &As[s][flat]);
            }
#pragma unroll
        for (int s = 0; s < SB; ++s)
#pragma unroll
            for (int it = 0; it < 2; ++it) {
                int flat = (it * 256 + tid) * 8;
                int row = flat >> 5;
                int blk = (flat >> 3) & 3;
                int ko = ((blk ^ ((row >> 1) & 3)) << 3);
                ld_lds16(B + (size_t)(bn + row) * ldB + s * Kp + kbase + ko, &Bs[s][flat]);
            }
        __syncthreads();
        half8 af[SA][4], bfr[SB][4];
#pragma unroll
        for (int s = 0; s < SA; ++s)
#pragma unroll
            for (int mi = 0; mi < 4; ++mi)
                af[s][mi] = *(const half8*)&As[s][(wm * 64 + mi * 16 + r_i) * 32 + sw];
#pragma unroll
        for (int s = 0; s < SB; ++s)
#pragma unroll
            for (int mi = 0; mi < 4; ++mi)
                bfr[s][mi] = *(const half8*)&Bs[s][(wn * 64 + mi * 16 + r_i) * 32 + sw];
#pragma unroll
        for (int i = 0; i < SA; ++i)
#pragma unroll
            for (int j = 0; j < SB; ++j) {
                if (i + j >= 2) continue;
#pragma unroll
                for (int mi = 0; mi < 4; ++mi)
#pragma unroll
                    for (int ni = 0; ni < 4; ++ni)
                        acc[mi][ni] = __builtin_amdgcn_mfma_f32_16x16x32_f16(
                            af[i][mi], bfr[j][ni], acc[mi][ni], 0, 0, 0);
            }
        __syncthreads();
    }
#pragma unroll
    for (int mi = 0; mi < 4; ++mi)
#pragma unroll
        for (int ni = 0; ni < 4; ++ni)
#pragma unroll
            for (int r = 0; r < 4; ++r) {
                int gm = bm + wm * 64 + mi * 16 + quad * 4 + r;
                int gn = bn + wn * 64 + ni * 16 + r_i;
                if (gm >= M || gn >= N) continue;
                float v = acc[mi][ni][r];
                if (splits > 1) {
                    Cpart[((size_t)z * M + gm) * N + gn] = v;  // raw; osc in epi_k
                } else {
                    v *= osc;
                    if (EPI == ERELU) v = fmaxf(v, 0.f);
                    else if (EPI == ESIG) v = 1.f / (1.f + expf(-v));
                    dst[(size_t)gm * ldc + coloff + gn] = v;
                }
            }
}

template <int EPI>
__global__ void epi_k(const float* __restrict__ Cpart, int splits, int M, int N,
                      float* __restrict__ dst, int ldc, int coloff, float osc) {
    int idx = blockIdx.x * 256 + threadIdx.x;
    if (idx >= M * N) return;
    size_t stride = (size_t)M * N;
    float v = 0.f;
    for (int s = 0; s < splits; ++s) v += Cpart[s * stride + idx];
    v *= osc;
    int m = idx / N, n = idx - m * N;
    if (EPI == ERELU) v = fmaxf(v, 0.f);
    else if (EPI == ESIG) v = 1.f / (1.f + expf(-v));
    dst[(size_t)m * ldc + coloff + n] = v;
}

// ---------------- host-side GEMM helpers ----------------
static inline int pick_splits(int nt, int mt, int Ma, int N, int ktiles, size_t cpn) {
    int tiles = nt * mt;
    if (tiles >= 256) return 1;
    int cap = (int)(cpn / ((size_t)Ma * N));
    int s = cdiv(768, tiles);                  // target ~3 blocks/CU
    if (s > cap) s = cap;
    if (s > ktiles) s = ktiles;
    if (s > 16) s = 16;
    if (s < 1) s = 1;
    return s;
}

template <int SA, int SB, int EPI>
static void gemm_packedA(hipStream_t s, const unsigned short* Ap, int ldA,
                         int M, int Kp, const unsigned short* Bp, int ldB, int N,
                         float* Cpart, size_t cpn, float* dst, int ldc, int coloff,
                         float osc) {
    int Ma = cdiv(M, 128) * 128;
    int ktiles = Kp / 32;
    int splits = pick_splits(cdiv(N, 128), Ma / 128, Ma, N, ktiles, cpn);
    dim3 g(cdiv(N, 128), Ma / 128, splits);
    if (splits == 1) {
        gemm_bt_k<SA, SB, EPI><<<g, 256, 0, s>>>(Ap, ldA, Bp, ldB, Kp, ktiles, 1, nullptr,
                                                 dst, ldc, coloff, M, N, osc);
    } else {
        gemm_bt_k<SA, SB, EPI><<<g, 256, 0, s>>>(Ap, ldA, Bp, ldB, Kp, ktiles, splits, Cpart,
                                                 nullptr, 0, 0, M, N, osc);
        epi_k<EPI><<<cdiv(M * N, 256), 256, 0, s>>>(Cpart, splits, M, N, dst, ldc, coloff, osc);
    }
}

template <int SA, int SB, int EPI>
static void gemm_rowsA(hipStream_t s,
                       const float* Asrc, int Mtot, int Kact, int Kp,
                       const float* rsc, const float* csc, float cscA,
                       unsigned short* PA, size_t PAelems,
                       const unsigned short* Bp, int ldB, int N,
                       float* Cpart, size_t cpn, float* dst, int ldc, int coloff,
                       float osc) {
    int ldA = SA * Kp;
    int maxCM = (int)((PAelems / (size_t)ldA) / 128) * 128;
    if (maxCM < 128) maxCM = 128;
    int ktiles = Kp / 32;
    for (int r0 = 0; r0 < Mtot; r0 += maxCM) {
        int Mv = (Mtot - r0 < maxCM) ? (Mtot - r0) : maxCM;
        int Ma = cdiv(Mv, 128) * 128;
        pack_rows_k<<<Ma, 256, 0, s>>>(Asrc, Mtot, Kact, r0, Kp, SA, ldA, rsc, csc, cscA, PA);
        int splits = pick_splits(cdiv(N, 128), Ma / 128, Ma, N, ktiles, cpn);
        dim3 g(cdiv(N, 128), Ma / 128, splits);
        if (splits == 1) {
            gemm_bt_k<SA, SB, EPI><<<g, 256, 0, s>>>(PA, ldA, Bp, ldB, Kp, ktiles, 1, nullptr,
                                                     dst + (size_t)r0 * ldc, ldc, coloff, Mv, N, osc);
        } else {
            gemm_bt_k<SA, SB, EPI><<<g, 256, 0, s>>>(PA, ldA, Bp, ldB, Kp, ktiles, splits, Cpart,
                                                     nullptr, 0, 0, Mv, N, osc);
            epi_k<EPI><<<cdiv(Mv * N, 256), 256, 0, s>>>(Cpart, splits, Mv, N,
                                                         dst + (size_t)r0 * ldc, ldc, coloff, osc);
        }
    }
}

template <int SA, int SB, int EPI>
static void gemm_transA(hipStream_t s,
                        const float* Asrc, int Mtot, int Kact, int Kp,
                        const float* ks, const float* ns, float cscA,
                        unsigned short* PA, size_t PAelems,
                        const unsigned short* Bp, int ldB, int N,
                        float* Cpart, size_t cpn, float* dst, int ldc, int coloff,
                        float osc) {
    int ldA = SA * Kp;
    int maxCM = (int)((PAelems / (size_t)ldA) / 128) * 128;
    if (maxCM < 128) maxCM = 128;
    int ktiles = Kp / 32;
    for (int r0 = 0; r0 < Mtot; r0 += maxCM) {
        int Mv = (Mtot - r0 < maxCM) ? (Mtot - r0) : maxCM;
        int Ma = cdiv(Mv, 128) * 128;
        pack_trans_k<<<dim3(Ma / 32, ktiles), 256, 0, s>>>(Asrc, Kact, Mtot, r0, Kp, SA, ldA,
                                                           ks, ns, cscA, PA);
        int splits = pick_splits(cdiv(N, 128), Ma / 128, Ma, N, ktiles, cpn);
        dim3 g(cdiv(N, 128), Ma / 128, splits);
        if (splits == 1) {
            gemm_bt_k<SA, SB, EPI><<<g, 256, 0, s>>>(PA, ldA, Bp, ldB, Kp, ktiles, 1, nullptr,
                                                     dst + (size_t)r0 * ldc, ldc, coloff, Mv, N, osc);
        } else {
            gemm_bt_k<SA, SB, EPI><<<g, 256, 0, s>>>(PA, ldA, Bp, ldB, Kp, ktiles, splits, Cpart,
                                                     nullptr, 0, 0, Mv, N, osc);
            epi_k<EPI><<<cdiv(Mv * N, 256), 256, 0, s>>>(Cpart, splits, Mv, N,
                                                         dst + (size_t)r0 * ldc, ldc, coloff, osc);
        }
    }
}

// ---------------- fallback fp32 SGEMM (round-1 proven path) ----------------
#define BM 64
#define BN 64
#define BK 16

template <bool TA, bool TB, int EPI>
__global__ __launch_bounds__(256) void gemm_f32_k(
    int M, int N, int K,
    const float* __restrict__ A, int lda,
    const float* __restrict__ B, int ldb,
    float* __restrict__ C, int ldc,
    const float* __restrict__ scaleB,
    const float* __restrict__ scaleC) {
    __shared__ float Asf[BK][BM + 4];
    __shared__ float Bsf[BK][BN + 4];
    int bn = blockIdx.x * BN;
    int bm = blockIdx.y * BM;
    int tid = threadIdx.x;
    int tx = tid & 15;
    int ty = tid >> 4;
    float acc[4][4] = {};
    for (int t = 0; t < K; t += BK) {
#pragma unroll
        for (int it = 0; it < (BM * BK) / 256; ++it) {
            int l = tid + it * 256;
            int k, m;
            if (TA) { k = l / BM; m = l % BM; }
            else    { m = l / BK; k = l % BK; }
            int gm = bm + m, gk = t + k;
            float v = 0.f;
            if (gm < M && gk < K)
                v = TA ? A[(size_t)gk * lda + gm] : A[(size_t)gm * lda + gk];
            Asf[k][m] = v;
        }
#pragma unroll
        for (int it = 0; it < (BN * BK) / 256; ++it) {
            int l = tid + it * 256;
            int k, n;
            if (TB) { n = l / BK; k = l % BK; }
            else    { k = l / BN; n = l % BN; }
            int gn = bn + n, gk = t + k;
            float v = 0.f;
            if (gn < N && gk < K) {
                v = TB ? B[(size_t)gn * ldb + gk] : B[(size_t)gk * ldb + gn];
                if (scaleB) v *= scaleB[gk];
            }
            Bsf[k][n] = v;
        }
        __syncthreads();
#pragma unroll
        for (int kk = 0; kk < BK; ++kk) {
            float a[4], b[4];
#pragma unroll
            for (int i = 0; i < 4; ++i) a[i] = Asf[kk][ty * 4 + i];
#pragma unroll
            for (int j = 0; j < 4; ++j) b[j] = Bsf[kk][tx * 4 + j];
#pragma unroll
            for (int i = 0; i < 4; ++i)
#pragma unroll
                for (int j = 0; j < 4; ++j)
                    acc[i][j] = fmaf(a[i], b[j], acc[i][j]);
        }
        __syncthreads();
    }
#pragma unroll
    for (int i = 0; i < 4; ++i) {
        int gm = bm + ty * 4 + i;
        if (gm >= M) continue;
#pragma unroll
        for (int j = 0; j < 4; ++j) {
            int gn = bn + tx * 4 + j;
            if (gn >= N) continue;
            float v = acc[i][j];
            if (EPI == ERELUSC) v = fmaxf(scaleC[gm] * v, 0.f);
            else if (EPI == ERELU) v = fmaxf(v, 0.f);
            else if (EPI == ESIG) v = 1.f / (1.f + expf(-v));
            C[(size_t)gm * ldc + gn] = v;
        }
    }
}

template <bool TA, bool TB, int EPI>
static inline void launch_gemm_f32(int M, int N, int K,
                                   const float* A, int lda,
                                   const float* B, int ldb,
                                   float* C, int ldc,
                                   const float* sB, const float* sC,
                                   hipStream_t stream) {
    dim3 grid((N + BN - 1) / BN, (M + BM - 1) / BM);
    gemm_f32_k<TA, TB, EPI><<<grid, dim3(256), 0, stream>>>(M, N, K, A, lda, B, ldb, C, ldc, sB, sC);
}

static void run_fp32_path(void* const* d_in, void* d_out, void* d_ws, hipStream_t stream) {
    const float* R   = (const float*)d_in[0];
    const float* D   = (const float*)d_in[1];
    const float* T   = (const float*)d_in[2];
    const float* H_d = (const float*)d_in[3];
    const float* H_t = (const float*)d_in[4];
    const float* W1g[2] = {(const float*)d_in[5], (const float*)d_in[7]};
    const float* W2g[2] = {(const float*)d_in[6], (const float*)d_in[8]};
    const float* Wd[3]  = {(const float*)d_in[9],  (const float*)d_in[11], (const float*)d_in[13]};
    const float* Wt[3]  = {(const float*)d_in[10], (const float*)d_in[12], (const float*)d_in[14]};
    float* out = (float*)d_out;
    float* ws = (float*)d_ws;
    size_t o = 0;
    auto alloc = [&](size_t n) { float* p = ws + o; o += n; return p; };
    float* sd   = alloc(DNUM);
    float* st   = alloc(TNUM);
    float* rdR  = alloc(DNUM);
    float* rtR  = alloc(TNUM);
    float* rd   = alloc(DNUM);
    float* rt   = alloc(TNUM);
    float* hd1  = alloc((size_t)DNUM * UNITS);
    float* ht1  = alloc((size_t)TNUM * UNITS);
    float* hd2  = alloc((size_t)DNUM * UNITS);
    float* ht2  = alloc((size_t)TNUM * UNITS);
    float* GHd  = alloc((size_t)DNUM * UNITS);
    float* GHt  = alloc((size_t)TNUM * UNITS);
    float* tv   = alloc((size_t)DNUM * TOPK);
    int*   ti   = (int*)alloc((size_t)DNUM * TOPK);
    float* accT = alloc((size_t)TNUM * FEAT);
    float* Cd   = alloc((size_t)DNUM * 3 * FEAT);
    float* Ct   = alloc((size_t)TNUM * 3 * FEAT);

    rowsum_rsqrt_k<<<DNUM, 256, 0, stream>>>(D, DNUM, sd);
    rowsum_rsqrt_k<<<TNUM, 256, 0, stream>>>(T, TNUM, st);
    rowsum_rsqrt_k<<<DNUM, 256, 0, stream>>>(R, TNUM, rdR);
    fill_zero_k<<<cdiv(TNUM, 256), 256, 0, stream>>>(rtR, TNUM);
    colsum_partial_k<<<dim3(cdiv(TNUM, 256), 32), 256, 0, stream>>>(R, DNUM, TNUM, rtR);
    rsqrt_safe_k<<<cdiv(TNUM, 256), 256, 0, stream>>>(rtR, TNUM);

    const float* hd_in = H_d;
    const float* ht_in = H_t;
    for (int l = 0; l < 2; ++l) {
        int F = (l == 0) ? FEAT : UNITS;
        int ld3 = 3 * F;
        launch_gemm_f32<false, false, ENONE>(DNUM, UNITS, F, hd_in, F, W1g[l], UNITS, GHd, UNITS, nullptr, nullptr, stream);
        launch_gemm_f32<false, false, ENONE>(TNUM, UNITS, F, ht_in, F, W2g[l], UNITS, GHt, UNITS, nullptr, nullptr, stream);
        launch_gemm_f32<false, true, ESIG>(DNUM, TNUM, UNITS, GHd, UNITS, GHt, UNITS, out, TNUM, nullptr, nullptr, stream);
        topk_k<<<DNUM, 256, 0, stream>>>(out, TNUM, tv, ti, rd);
        fill_zero_k<<<cdiv(TNUM, 256), 256, 0, stream>>>(rt, TNUM);
        scatter_colsum_k<<<cdiv(DNUM * TOPK, 256), 256, 0, stream>>>(tv, ti, rt, DNUM * TOPK);
        rsqrt_safe_k<<<cdiv(TNUM, 256), 256, 0, stream>>>(rt, TNUM);
        gather_hdt_k<<<DNUM, 256, 0, stream>>>(tv, ti, rt, rd, ht_in, F, Cd, ld3, F);
        fill_zero_k<<<cdiv(TNUM * F, 256), 256, 0, stream>>>(accT, TNUM * F);
        scatter_htd_k<<<DNUM, 256, 0, stream>>>(tv, ti, rd, hd_in, F, accT);
        finalize_htd_k<<<TNUM, 256, 0, stream>>>(accT, rt, F, Ct, ld3, F);
        copy_rows_k<<<DNUM, 256, 0, stream>>>(hd_in, F, Cd, ld3);
        copy_rows_k<<<TNUM, 256, 0, stream>>>(ht_in, F, Ct, ld3);
        launch_gemm_f32<false, false, ERELUSC>(DNUM, F, DNUM, D, DNUM, hd_in, F, Cd + 2 * F, ld3, sd, sd, stream);
        launch_gemm_f32<false, false, ERELUSC>(TNUM, F, TNUM, T, TNUM, ht_in, F, Ct + 2 * F, ld3, st, st, stream);
        float* hdo = (l == 0) ? hd1 : hd2;
        float* hto = (l == 0) ? ht1 : ht2;
        launch_gemm_f32<false, false, ERELU>(DNUM, UNITS, 3 * F, Cd, ld3, Wd[l], UNITS, hdo, UNITS, nullptr, nullptr, stream);
        launch_gemm_f32<false, false, ERELU>(TNUM, UNITS, 3 * F, Ct, ld3, Wt[l], UNITS, hto, UNITS, nullptr, nullptr, stream);
        hd_in = hdo;
        ht_in = hto;
    }
    {
        int F = UNITS, ld3 = 3 * UNITS;
        launch_gemm_f32<false, false, ERELUSC>(DNUM, F, TNUM, R, TNUM, ht_in, F, Cd + F, ld3, rtR, rdR, stream);
        launch_gemm_f32<true, false, ERELUSC>(TNUM, F, DNUM, R, TNUM, hd_in, F, Ct + F, ld3, rdR, rtR, stream);
        copy_rows_k<<<DNUM, 256, 0, stream>>>(hd_in, F, Cd, ld3);
        copy_rows_k<<<TNUM, 256, 0, stream>>>(ht_in, F, Ct, ld3);
        launch_gemm_f32<false, false, ERELUSC>(DNUM, F, DNUM, D, DNUM, hd_in, F, Cd + 2 * F, ld3, sd, sd, stream);
        launch_gemm_f32<false, false, ERELUSC>(TNUM, F, TNUM, T, TNUM, ht_in, F, Ct + 2 * F, ld3, st, st, stream);
        launch_gemm_f32<false, false, ERELU>(DNUM, UNITS, 3 * F, Cd, ld3, Wd[2], UNITS, hd1, UNITS, nullptr, nullptr, stream);
        launch_gemm_f32<false, false, ERELU>(TNUM, UNITS, 3 * F, Ct, ld3, Wt[2], UNITS, ht1, UNITS, nullptr, nullptr, stream);
        launch_gemm_f32<false, true, ESIG>(DNUM, TNUM, UNITS, hd1, UNITS, ht1, UNITS, out, TNUM, nullptr, nullptr, stream);
    }
}

// ---------------- main driver ----------------
extern "C" void kernel_launch(void* const* d_in, const int* in_sizes, int n_in,
                              void* d_out, int out_size, void* d_ws, size_t ws_size,
                              hipStream_t stream) {
    (void)in_sizes; (void)n_in; (void)out_size;
    const float* R   = (const float*)d_in[0];
    const float* D   = (const float*)d_in[1];
    const float* T   = (const float*)d_in[2];
    const float* H_d = (const float*)d_in[3];
    const float* H_t = (const float*)d_in[4];
    const float* W1g[2] = {(const float*)d_in[5], (const float*)d_in[7]};
    const float* W2g[2] = {(const float*)d_in[6], (const float*)d_in[8]};
    const float* Wd[3]  = {(const float*)d_in[9],  (const float*)d_in[11], (const float*)d_in[13]};
    const float* Wt[3]  = {(const float*)d_in[10], (const float*)d_in[12], (const float*)d_in[14]};
    float* out = (float*)d_out;   // [4000,2000]; doubles as GL score scratch

    const int KpD = 4000, KpT = 2016, KpU = 224;
    const int KpF0 = 256;
    const int Kp3F0 = 768, Kp3F1 = 608;

    // f16-split range scales (exact powers of two; undone by osc in epilogue)
    const float SH = 16.f;     // feature matrices (H, GH, Cd, hd1...)  |v| <~ 30
    const float SW = 64.f;     // glorot weights                        |v| <~ 0.12
    const float SG = 2048.f;   // norm-scaled graphs D-hat/T-hat/R-hat  |v| <~ 1e-3..1
    const float OHW = 1.f / (16.f * 64.f);
    const float OHH = 1.f / (16.f * 16.f);
    const float OGH = 1.f / (2048.f * 16.f);

    char* base = (char*)d_ws;
    size_t off = 0;
    auto alloc = [&](size_t bytes) -> void* {
        off = (off + 255) & ~(size_t)255;
        void* p = base + off;
        off += bytes;
        return p;
    };
    float* sd   = (float*)alloc(DNUM * 4);
    float* st   = (float*)alloc(TNUM * 4);
    float* rdR  = (float*)alloc(DNUM * 4);
    float* rtR  = (float*)alloc(TNUM * 4);
    float* rdv  = (float*)alloc(DNUM * 4);
    float* rt   = (float*)alloc(TNUM * 4);
    float* hd1  = (float*)alloc((size_t)DNUM * UNITS * 4);
    float* ht1  = (float*)alloc((size_t)TNUM * UNITS * 4);
    float* hd2  = (float*)alloc((size_t)DNUM * UNITS * 4);
    float* ht2  = (float*)alloc((size_t)TNUM * UNITS * 4);
    float* GHd  = (float*)alloc((size_t)DNUM * UNITS * 4);
    float* GHt  = (float*)alloc((size_t)TNUM * UNITS * 4);
    float* tv   = (float*)alloc((size_t)DNUM * TOPK * 4);
    int*   ti   = (int*)alloc((size_t)DNUM * TOPK * 4);
    float* accT = (float*)alloc((size_t)TNUM * FEAT * 4);
    float* Cd   = (float*)alloc((size_t)DNUM * 3 * FEAT * 4);
    float* Ct   = (float*)alloc((size_t)TNUM * 3 * FEAT * 4);
    unsigned short* PB = (unsigned short*)alloc((size_t)3200000 * 2);  // B packs

    // ---- tiered workspace plan (1-split A packs for graphs, 2-split B) ----
    const size_t PA_DYN = (size_t)4096 * 4032 * 2;    // 33.0 MB dynamic A packs
    const size_t DP_B   = (size_t)4096 * 4000 * 2;    // persistent 1-split D-hat
    const size_t TP_B   = (size_t)2048 * 2016 * 2;    // persistent 1-split T-hat
    const size_t RP_B   = (size_t)2048 * 4000 * 2;    // persistent dense 1-split R-filter
    const size_t CP_MIN = (size_t)8 * 1024 * 1024 * 4;
    bool persist = false;
    unsigned short *Dp = nullptr, *Tp = nullptr, *Rp = nullptr, *PA = nullptr;
    float* Cpart = nullptr;
    size_t cpn = 0, PAelems = 0;
    {
        size_t aligned_off = (off + 255) & ~(size_t)255;
        if (ws_size >= aligned_off + PA_DYN + DP_B + TP_B + RP_B + CP_MIN + 1024) {
            persist = true;
            PA = (unsigned short*)alloc(PA_DYN);  PAelems = PA_DYN / 2;
            Dp = (unsigned short*)alloc(DP_B);
            Tp = (unsigned short*)alloc(TP_B);
            Rp = (unsigned short*)alloc(RP_B);
            off = (off + 255) & ~(size_t)255;
            size_t cb = ws_size - off;
            if (cb > (size_t)64 * 1024 * 1024 * 4) cb = (size_t)64 * 1024 * 1024 * 4;
            Cpart = (float*)(base + off);
            cpn = cb / 4;
        } else {
            // fallback: shared PA, fixed Cpart, legacy scatter H_td
            const size_t PA_FULL = (size_t)4096 * 8000 * 2;
            const size_t PA_MINB = (size_t)1024 * 8000 * 2;
            const size_t CP_BIG = (size_t)8 * 1024 * 1024 * 4;
            const size_t CP_SML = (size_t)4 * 1024 * 1024 * 4;
            size_t rem = (ws_size > aligned_off) ? ws_size - aligned_off : 0;
            size_t cpart_bytes;
            if (rem >= PA_FULL + CP_BIG + 512)      cpart_bytes = CP_BIG;
            else if (rem >= PA_FULL + CP_SML + 512) cpart_bytes = CP_SML;
            else if (rem >= PA_MINB + CP_SML + 512) cpart_bytes = CP_SML;
            else { run_fp32_path(d_in, d_out, d_ws, stream); return; }
            Cpart = (float*)alloc(cpart_bytes);
            cpn = cpart_bytes / 4;
            off = (off + 255) & ~(size_t)255;
            PA = (unsigned short*)(base + off);
            PAelems = (ws_size - off) / 2;
        }
    }

    // ---- norm vectors ----
    rowsum_rsqrt_k<<<DNUM, 256, 0, stream>>>(D, DNUM, sd);
    rowsum_rsqrt_k<<<TNUM, 256, 0, stream>>>(T, TNUM, st);
    rowsum_rsqrt_k<<<DNUM, 256, 0, stream>>>(R, TNUM, rdR);
    fill_zero_k<<<cdiv(TNUM, 256), 256, 0, stream>>>(rtR, TNUM);
    colsum_partial_k<<<dim3(cdiv(TNUM, 256), 32), 256, 0, stream>>>(R, DNUM, TNUM, rtR);
    rsqrt_safe_k<<<cdiv(TNUM, 256), 256, 0, stream>>>(rtR, TNUM);

    // ---- persistent packs: D-hat & T-hat once (1-split); zero R-filter ----
    if (persist) {
        pack_rows_k<<<4096, 256, 0, stream>>>(D, DNUM, DNUM, 0, KpD, 1, KpD, sd, sd, SG, Dp);
        pack_rows_k<<<2048, 256, 0, stream>>>(T, TNUM, TNUM, 0, KpT, 1, KpT, st, st, SG, Tp);
        fill_zero_k<<<cdiv((int)(RP_B / 4), 256), 256, 0, stream>>>((float*)Rp, (int)(RP_B / 4));
    }

    const float* hd_in = H_d;
    const float* ht_in = H_t;
    for (int l = 0; l < 2; ++l) {
        int F = (l == 0) ? FEAT : UNITS;
        int KpF = (l == 0) ? KpF0 : KpU;
        int Kp3 = (l == 0) ? Kp3F0 : Kp3F1;
        int ld3 = 3 * F;
        // ---- GL scoring (full 2x2-split: keeps top-k stable) ----
        pack_trans_k<<<dim3(8, KpF / 32), 256, 0, stream>>>(W1g[l], F, UNITS, 0, KpF, 2, 2 * KpF, nullptr, nullptr, SW, PB);
        gemm_rowsA<2, 2, ENONE>(stream, hd_in, DNUM, F, KpF, nullptr, nullptr, SH, PA, PAelems,
                                PB, 2 * KpF, UNITS, Cpart, cpn, GHd, UNITS, 0, OHW);
        pack_trans_k<<<dim3(8, KpF / 32), 256, 0, stream>>>(W2g[l], F, UNITS, 0, KpF, 2, 2 * KpF, nullptr, nullptr, SW, PB);
        gemm_rowsA<2, 2, ENONE>(stream, ht_in, TNUM, F, KpF, nullptr, nullptr, SH, PA, PAelems,
                                PB, 2 * KpF, UNITS, Cpart, cpn, GHt, UNITS, 0, OHW);
        pack_rows_k<<<2048, 256, 0, stream>>>(GHt, TNUM, UNITS, 0, KpU, 2, 2 * KpU, nullptr, nullptr, SH, PB);
        gemm_rowsA<2, 2, ESIG>(stream, GHd, DNUM, UNITS, KpU, nullptr, nullptr, SH, PA, PAelems,
                               PB, 2 * KpU, TNUM, Cpart, cpn, out, TNUM, 0, OHH);
        // ---- top-k + sparse CGC terms ----
        topk_wave_k<<<DNUM / 4, 256, 0, stream>>>(out, TNUM, tv, ti, rdv);
        fill_zero_k<<<cdiv(TNUM, 256), 256, 0, stream>>>(rt, TNUM);
        colsum_lds_k<<<cdiv(DNUM * TOPK, CS_ENT), 256, 0, stream>>>(tv, ti, rt, DNUM * TOPK);
        rsqrt_safe_k<<<cdiv(TNUM, 256), 256, 0, stream>>>(rt, TNUM);
        gather_hdt_k<<<DNUM, 256, 0, stream>>>(tv, ti, rt, rdv, ht_in, F, Cd, ld3, F);
        copy_rows_k<<<DNUM, 256, 0, stream>>>(hd_in, F, Cd, ld3);
        copy_rows_k<<<TNUM, 256, 0, stream>>>(ht_in, F, Ct, ld3);
        // ---- dense graph convs + H_td (1-split graph A x 2-split hd B) ----
        pack_trans_k<<<dim3(8, KpD / 32), 256, 0, stream>>>(hd_in, DNUM, F, 0, KpD, 2, 2 * KpD, nullptr, nullptr, SH, PB);
        if (persist) {
            place_rp_k<<<cdiv(DNUM * TOPK, 256), 256, 0, stream>>>(tv, ti, rdv, rt, KpD, SG, Rp);
            gemm_packedA<1, 2, ERELU>(stream, Rp, KpD, TNUM, KpD, PB, 2 * KpD, F, Cpart, cpn, Ct, ld3, F, OGH);
            gemm_packedA<1, 2, ERELU>(stream, Dp, KpD, DNUM, KpD, PB, 2 * KpD, F, Cpart, cpn, Cd, ld3, 2 * F, OGH);
            zero_rp_k<<<cdiv(DNUM * TOPK, 256), 256, 0, stream>>>(ti, KpD, Rp);
        } else {
            fill_zero_k<<<cdiv(TNUM * F, 256), 256, 0, stream>>>(accT, TNUM * F);
            scatter_htd_k<<<DNUM, 256, 0, stream>>>(tv, ti, rdv, hd_in, F, accT);
            finalize_htd_k<<<TNUM, 256, 0, stream>>>(accT, rt, F, Ct, ld3, F);
            gemm_rowsA<1, 2, ERELU>(stream, D, DNUM, DNUM, KpD, sd, sd, SG, PA, PAelems,
                                    PB, 2 * KpD, F, Cpart, cpn, Cd, ld3, 2 * F, OGH);
        }
        pack_trans_k<<<dim3(8, KpT / 32), 256, 0, stream>>>(ht_in, TNUM, F, 0, KpT, 2, 2 * KpT, nullptr, nullptr, SH, PB);
        if (persist)
            gemm_packedA<1, 2, ERELU>(stream, Tp, KpT, TNUM, KpT, PB, 2 * KpT, F, Cpart, cpn, Ct, ld3, 2 * F, OGH);
        else
            gemm_rowsA<1, 2, ERELU>(stream, T, TNUM, TNUM, KpT, st, st, SG, PA, PAelems,
                                    PB, 2 * KpT, F, Cpart, cpn, Ct, ld3, 2 * F, OGH);
        pack_trans_k<<<dim3(8, Kp3 / 32), 256, 0, stream>>>(Wd[l], 3 * F, UNITS, 0, Kp3, 2, 2 * Kp3, nullptr, nullptr, SW, PB);
        float* hdo = (l == 0) ? hd1 : hd2;
        gemm_rowsA<2, 2, ERELU>(stream, Cd, DNUM, 3 * F, Kp3, nullptr, nullptr, SH, PA, PAelems,
                                PB, 2 * Kp3, UNITS, Cpart, cpn, hdo, UNITS, 0, OHW);
        pack_trans_k<<<dim3(8, Kp3 / 32), 256, 0, stream>>>(Wt[l], 3 * F, UNITS, 0, Kp3, 2, 2 * Kp3, nullptr, nullptr, SW, PB);
        float* hto = (l == 0) ? ht1 : ht2;
        gemm_rowsA<2, 2, ERELU>(stream, Ct, TNUM, 3 * F, Kp3, nullptr, nullptr, SH, PA, PAelems,
                                PB, 2 * Kp3, UNITS, Cpart, cpn, hto, UNITS, 0, OHW);
        hd_in = hdo;
        ht_in = hto;
    }

    // ---- output CGC on original dense graphs ----
    {
        int F = UNITS, ld3 = 3 * UNITS, Kp3 = Kp3F1;
        pack_trans_k<<<dim3(8, KpT / 32), 256, 0, stream>>>(ht_in, TNUM, F, 0, KpT, 2, 2 * KpT, nullptr, nullptr, SH, PB);
        gemm_rowsA<1, 2, ERELU>(stream, R, DNUM, TNUM, KpT, rdR, rtR, SG, PA, PAelems,
                                PB, 2 * KpT, F, Cpart, cpn, Cd, ld3, F, OGH);
        pack_trans_k<<<dim3(8, KpD / 32), 256, 0, stream>>>(hd_in, DNUM, F, 0, KpD, 2, 2 * KpD, nullptr, nullptr, SH, PB);
        gemm_transA<1, 2, ERELU>(stream, R, TNUM, DNUM, KpD, rdR, rtR, SG, PA, PAelems,
                                 PB, 2 * KpD, F, Cpart, cpn, Ct, ld3, F, OGH);
        copy_rows_k<<<DNUM, 256, 0, stream>>>(hd_in, F, Cd, ld3);
        copy_rows_k<<<TNUM, 256, 0, stream>>>(ht_in, F, Ct, ld3);
        // H_dd: PB still holds the 2-split hd pack (ld 2*KpD)
        if (persist)
            gemm_packedA<1, 2, ERELU>(stream, Dp, KpD, DNUM, KpD, PB, 2 * KpD, F, Cpart, cpn, Cd, ld3, 2 * F, OGH);
        else
            gemm_rowsA<1, 2, ERELU>(stream, D, DNUM, DNUM, KpD, sd, sd, SG, PA, PAelems,
                                    PB, 2 * KpD, F, Cpart, cpn, Cd, ld3, 2 * F, OGH);
        pack_trans_k<<<dim3(8, KpT / 32), 256, 0, stream>>>(ht_in, TNUM, F, 0, KpT, 2, 2 * KpT, nullptr, nullptr, SH, PB);
        if (persist)
            gemm_packedA<1, 2, ERELU>(stream, Tp, KpT, TNUM, KpT, PB, 2 * KpT, F, Cpart, cpn, Ct, ld3, 2 * F, OGH);
        else
            gemm_rowsA<1, 2, ERELU>(stream, T, TNUM, TNUM, KpT, st, st, SG, PA, PAelems,
                                    PB, 2 * KpT, F, Cpart, cpn, Ct, ld3, 2 * F, OGH);
        pack_trans_k<<<dim3(8, Kp3 / 32), 256, 0, stream>>>(Wd[2], 3 * F, UNITS, 0, Kp3, 2, 2 * Kp3, nullptr, nullptr, SW, PB);
        gemm_rowsA<2, 2, ERELU>(stream, Cd, DNUM, 3 * F, Kp3, nullptr, nullptr, SH, PA, PAelems,
                                PB, 2 * Kp3, UNITS, Cpart, cpn, hd1, UNITS, 0, OHW);
        pack_trans_k<<<dim3(8, Kp3 / 32), 256, 0, stream>>>(Wt[2], 3 * F, UNITS, 0, Kp3, 2, 2 * Kp3, nullptr, nullptr, SW, PB);
        gemm_rowsA<2, 2, ERELU>(stream, Ct, TNUM, 3 * F, Kp3, nullptr, nullptr, SH, PA, PAelems,
                                PB, 2 * Kp3, UNITS, Cpart, cpn, ht1, UNITS, 0, OHW);
        // R_pred = sigmoid(hd1 @ ht1^T)  (full 2x2-split: output precision)
        pack_rows_k<<<2048, 256, 0, stream>>>(ht1, TNUM, UNITS, 0, KpU, 2, 2 * KpU, nullptr, nullptr, SH, PB);
        gemm_rowsA<2, 2, ESIG>(stream, hd1, DNUM, UNITS, KpU, nullptr, nullptr, SH, PA, PAelems,
                               PB, 2 * KpU, TNUM, Cpart, cpn, out, TNUM, 0, OHH);
    }
}

// Round 8
// 1134.086 us; speedup vs baseline: 1.1592x; 1.1592x over previous
//
#include <hip/hip_runtime.h>
#include <math.h>

#define DNUM 4000
#define TNUM 2000
#define FEAT 256
#define UNITS 200
#define TOPK 10
#define CS_ENT 1024

typedef __attribute__((ext_vector_type(8))) _Float16 half8;
typedef __attribute__((ext_vector_type(4))) float f32x4;
typedef __attribute__((ext_vector_type(4))) unsigned short us4;

enum { ENONE = 0, ERELU = 1, ERELUSC = 2, ESIG = 3 };

typedef unsigned int u32_g __attribute__((address_space(1)));
typedef unsigned int u32_l __attribute__((address_space(3)));

// fp16 split helpers (RNE via hardware cvt)
__device__ __forceinline__ unsigned short f2h(float x) {
    union { _Float16 h; unsigned short u; } v; v.h = (_Float16)x; return v.u;
}
__device__ __forceinline__ float h2f(unsigned short b) {
    union { _Float16 h; unsigned short u; } v; v.u = b; return (float)v.h;
}
__device__ __forceinline__ void ld_lds16(const void* g, void* l) {
    __builtin_amdgcn_global_load_lds((const u32_g*)g, (u32_l*)l, 16, 0, 0);
}

static inline int cdiv(int a, int b) { return (a + b - 1) / b; }

// ---------------- small utility kernels ----------------

__global__ void fill_zero_k(float* __restrict__ p, int n) {
    int i = blockIdx.x * 256 + threadIdx.x;
    if (i < n) p[i] = 0.f;
}

// out[r] = rsqrt(safe(rowsum)); cols must be %4 (4000/2000 are)
__global__ void rowsum_rsqrt_k(const float* __restrict__ A, int cols, float* __restrict__ out) {
    int r = blockIdx.x;
    int tid = threadIdx.x;
    const float* row = A + (size_t)r * cols;
    float s = 0.f;
    for (int j4 = tid * 4; j4 < cols; j4 += 1024) {
        f32x4 x = *(const f32x4*)&row[j4];
        s += x[0] + x[1] + x[2] + x[3];
    }
    __shared__ float red[256];
    red[tid] = s;
    __syncthreads();
    for (int st = 128; st > 0; st >>= 1) {
        if (tid < st) red[tid] += red[tid + st];
        __syncthreads();
    }
    if (tid == 0) {
        float n = red[0];
        out[r] = (n == 0.f) ? 1.f : (1.f / sqrtf(n));
    }
}

__global__ void colsum_partial_k(const float* __restrict__ A, int rows, int cols,
                                 float* __restrict__ out) {
    int j = blockIdx.x * 256 + threadIdx.x;
    if (j >= cols) return;
    int chunk = blockIdx.y, nch = gridDim.y;
    int r0 = (int)((long long)rows * chunk / nch);
    int r1 = (int)((long long)rows * (chunk + 1) / nch);
    float s = 0.f;
    for (int i = r0; i < r1; i++) s += A[(size_t)i * cols + j];
    atomicAdd(&out[j], s);
}

__global__ void rsqrt_safe_k(float* __restrict__ v, int n) {
    int i = blockIdx.x * 256 + threadIdx.x;
    if (i < n) {
        float x = v[i];
        v[i] = (x == 0.f) ? 1.f : (1.f / sqrtf(x));
    }
}

__global__ void copy_rows_k(const float* __restrict__ src, int F,
                            float* __restrict__ dst, int ldc) {
    int i = blockIdx.x;
    for (int f4 = threadIdx.x * 4; f4 < F; f4 += 1024)
        *(f32x4*)&dst[(size_t)i * ldc + f4] = *(const f32x4*)&src[(size_t)i * F + f4];
}

// ---------------- top-k ----------------
// Wave-per-row register top-k: no LDS, no barriers. One 64-lane wave per row,
// 4 rows per 256-thread block. Stable smaller-index-first tie order.
__global__ void topk_wave_k(const float* __restrict__ S, int cols,
                            float* __restrict__ tv, int* __restrict__ ti,
                            float* __restrict__ rd) {
    int wid = threadIdx.x >> 6;
    int lane = threadIdx.x & 63;
    int row = blockIdx.x * 4 + wid;
    const float* srow = S + (size_t)row * cols;
    float lv[TOPK];
    int li[TOPK];
#pragma unroll
    for (int m = 0; m < TOPK; ++m) { lv[m] = -3.0e38f; li[m] = 0x7fffffff; }
    for (int j = lane; j < cols; j += 64) {
        float v = srow[j];
        if (v > lv[TOPK - 1]) {
            lv[TOPK - 1] = v; li[TOPK - 1] = j;
#pragma unroll
            for (int p = TOPK - 1; p >= 1; --p) {
                if (lv[p] > lv[p - 1]) {
                    float tf = lv[p]; lv[p] = lv[p - 1]; lv[p - 1] = tf;
                    int   tn = li[p]; li[p] = li[p - 1]; li[p - 1] = tn;
                }
            }
        }
    }
    float ssum = 0.f;
#pragma unroll
    for (int m = 0; m < TOPK; ++m) {
        float cv = lv[0];
        int   ci = li[0];
#pragma unroll
        for (int d = 1; d < 64; d <<= 1) {
            float ov = __shfl_xor(cv, d);
            int   oi = __shfl_xor(ci, d);
            if (ov > cv || (ov == cv && oi < ci)) { cv = ov; ci = oi; }
        }
        ssum += cv;
        if (lane == m) {
            tv[(size_t)row * TOPK + m] = cv;
            ti[(size_t)row * TOPK + m] = ci;
        }
        if (li[0] == ci) {  // unique owner pops (compile-time-indexed shift)
#pragma unroll
            for (int p = 0; p < TOPK - 1; ++p) { lv[p] = lv[p + 1]; li[p] = li[p + 1]; }
            lv[TOPK - 1] = -3.0e38f; li[TOPK - 1] = 0x7fffffff;
        }
    }
    if (lane == 0) rd[row] = (ssum == 0.f) ? 1.f : (1.f / sqrtf(ssum));
}

// legacy block top-k (fp32 fallback path)
__global__ void topk_k(const float* __restrict__ S, int cols,
                       float* __restrict__ tv, int* __restrict__ ti,
                       float* __restrict__ rd) {
    int row = blockIdx.x;
    int tid = threadIdx.x;
    const float* srow = S + (size_t)row * cols;
    __shared__ float vals[2048];
    __shared__ float redv[256];
    __shared__ int   redi[256];
    __shared__ float selv[TOPK];
    __shared__ int   seli[TOPK];
    for (int j = tid; j < cols; j += 256) vals[j] = srow[j];
    __syncthreads();
    for (int it = 0; it < TOPK; ++it) {
        float bv = -3.0e38f;
        int bi = 0x7fffffff;
        for (int j = tid; j < cols; j += 256) {
            float v = vals[j];
            if (v > bv || (v == bv && j < bi)) { bv = v; bi = j; }
        }
        redv[tid] = bv; redi[tid] = bi;
        __syncthreads();
        for (int st = 128; st > 0; st >>= 1) {
            if (tid < st) {
                float v2 = redv[tid + st]; int i2 = redi[tid + st];
                if (v2 > redv[tid] || (v2 == redv[tid] && i2 < redi[tid])) {
                    redv[tid] = v2; redi[tid] = i2;
                }
            }
            __syncthreads();
        }
        if (tid == 0) {
            selv[it] = redv[0];
            seli[it] = redi[0];
            vals[redi[0]] = -3.0e38f;
        }
        __syncthreads();
    }
    if (tid < TOPK) {
        tv[(size_t)row * TOPK + tid] = selv[tid];
        ti[(size_t)row * TOPK + tid] = seli[tid];
    }
    if (tid == 0) {
        float s = 0.f;
        for (int m = 0; m < TOPK; m++) s += selv[m];
        rd[row] = (s == 0.f) ? 1.f : (1.f / sqrtf(s));
    }
}

// hub-safe column sum: LDS pre-aggregation (depth<=CS_ENT at ~4cy LDS atomics),
// then one global atomic per (block, nonzero t) -> hub depth <= #blocks.
__global__ void colsum_lds_k(const float* __restrict__ tv, const int* __restrict__ ti,
                             float* __restrict__ rt, int n) {
    __shared__ float acc[TNUM];
    int tid = threadIdx.x;
    for (int i = tid; i < TNUM; i += 256) acc[i] = 0.f;
    __syncthreads();
    int base = blockIdx.x * CS_ENT;
    int end = base + CS_ENT;
    if (end > n) end = n;
    for (int g = base + tid; g < end; g += 256)
        atomicAdd(&acc[ti[g]], tv[g]);
    __syncthreads();
    for (int i = tid; i < TNUM; i += 256) {
        float v = acc[i];
        if (v != 0.f) atomicAdd(&rt[i], v);
    }
}

// legacy direct scatter (fp32 fallback path)
__global__ void scatter_colsum_k(const float* __restrict__ tv, const int* __restrict__ ti,
                                 float* __restrict__ nt, int n) {
    int g = blockIdx.x * 256 + threadIdx.x;
    if (g < n) atomicAdd(&nt[ti[g]], tv[g]);
}

__global__ void gather_hdt_k(const float* __restrict__ tv, const int* __restrict__ ti,
                             const float* __restrict__ rt, const float* __restrict__ rd,
                             const float* __restrict__ ht, int F,
                             float* __restrict__ C, int ldc, int coloff) {
    int i = blockIdx.x;
    int tid = threadIdx.x;
    __shared__ float w[TOPK];
    __shared__ int   id[TOPK];
    if (tid < TOPK) {
        int idx = ti[(size_t)i * TOPK + tid];
        id[tid] = idx;
        w[tid] = tv[(size_t)i * TOPK + tid] * rt[idx];
    }
    __syncthreads();
    float s = rd[i];
    for (int f = tid; f < F; f += 256) {
        float acc = 0.f;
#pragma unroll
        for (int m = 0; m < TOPK; ++m)
            acc += w[m] * ht[(size_t)id[m] * F + f];
        C[(size_t)i * ldc + coloff + f] = fmaxf(s * acc, 0.f);
    }
}

// ---------------- dense-R H_td path (persist): place/clear sparse weights in a
// persistent 1-split f16 A-matrix; B reuses the hd K-major pack (PB).
__global__ void place_rp_k(const float* __restrict__ tv, const int* __restrict__ ti,
                           const float* __restrict__ rd, const float* __restrict__ rt,
                           int ldr, float cconst,
                           unsigned short* __restrict__ Rp) {
    int g = blockIdx.x * 256 + threadIdx.x;
    if (g >= DNUM * TOPK) return;
    int d = g / TOPK;
    int t = ti[g];
    float w = tv[g] * rd[d] * rt[t] * cconst;
    Rp[(size_t)t * ldr + d] = f2h(w);
}

__global__ void zero_rp_k(const int* __restrict__ ti, int ldr,
                          unsigned short* __restrict__ Rp) {
    int g = blockIdx.x * 256 + threadIdx.x;
    if (g >= DNUM * TOPK) return;
    int d = g / TOPK;
    int t = ti[g];
    Rp[(size_t)t * ldr + d] = 0;
}

// legacy scatter path (fp32 fallback / non-persist)
__global__ void scatter_htd_k(const float* __restrict__ tv, const int* __restrict__ ti,
                              const float* __restrict__ rd, const float* __restrict__ hd,
                              int F, float* __restrict__ accT) {
    int i = blockIdx.x;
    int tid = threadIdx.x;
    __shared__ float row[256];
    __shared__ float w[TOPK];
    __shared__ int   id[TOPK];
    for (int f = tid; f < F; f += 256) row[f] = hd[(size_t)i * F + f];
    if (tid < TOPK) {
        id[tid] = ti[(size_t)i * TOPK + tid];
        w[tid] = tv[(size_t)i * TOPK + tid] * rd[i];
    }
    __syncthreads();
    for (int m = 0; m < TOPK; ++m) {
        float wm = w[m];
        int j = id[m];
        for (int f = tid; f < F; f += 256)
            atomicAdd(&accT[(size_t)j * F + f], wm * row[f]);
    }
}

__global__ void finalize_htd_k(const float* __restrict__ accT, const float* __restrict__ rt,
                               int F, float* __restrict__ C, int ldc, int coloff) {
    int j = blockIdx.x;
    float s = rt[j];
    for (int f = threadIdx.x; f < F; f += 256)
        C[(size_t)j * ldc + coloff + f] = fmaxf(s * accT[(size_t)j * F + f], 0.f);
}

// ---------------- f16-split pack kernels (vectorized) ----------------
// All Kp, C, ld used here are multiples of 4; bases are 256B-aligned.
// cconst: exact power-of-2 scale so primary AND residual stay f16-normal;
// it is undone via osc in the GEMM epilogue (exact round trip).
__global__ void pack_rows_k(const float* __restrict__ X, int Rtot, int C, int r0,
                            int Kp, int NS, int ld,
                            const float* __restrict__ rs, const float* __restrict__ cs,
                            float cconst,
                            unsigned short* __restrict__ out) {
    int l = blockIdx.x;
    int r = r0 + l;
    unsigned short* orow = out + (size_t)l * ld;
    if (r >= Rtot) {
        us4 z = {0, 0, 0, 0};
        for (int c4 = threadIdx.x * 4; c4 < NS * Kp; c4 += 1024)
            *(us4*)&orow[c4] = z;
        return;
    }
    float rsc = (rs ? rs[r] : 1.f) * cconst;
    const float* xrow = X + (size_t)r * C;
    for (int c4 = threadIdx.x * 4; c4 < Kp; c4 += 1024) {
        float v[4];
        if (c4 + 4 <= C) {
            f32x4 x = *(const f32x4*)&xrow[c4];
            v[0] = x[0]; v[1] = x[1]; v[2] = x[2]; v[3] = x[3];
        } else {
#pragma unroll
            for (int j = 0; j < 4; ++j) v[j] = (c4 + j < C) ? xrow[c4 + j] : 0.f;
        }
        us4 b0v, b1v;
#pragma unroll
        for (int j = 0; j < 4; ++j) {
            float val = v[j] * rsc;
            if (cs && c4 + j < C) val *= cs[c4 + j];
            unsigned short b0 = f2h(val);
            b0v[j] = b0;
            b1v[j] = f2h(val - h2f(b0));
        }
        *(us4*)&orow[c4] = b0v;
        if (NS >= 2) *(us4*)&orow[Kp + c4] = b1v;
    }
}

__global__ void pack_trans_k(const float* __restrict__ X, int Kact, int Ctot, int c0base,
                             int Kp, int NS, int ld,
                             const float* __restrict__ ks, const float* __restrict__ ns,
                             float cconst,
                             unsigned short* __restrict__ out) {
    __shared__ float tile[32][33];
    int c0 = blockIdx.x * 32, k0 = blockIdx.y * 32;
    int ci = threadIdx.x & 31, kq = threadIdx.x >> 5;
    for (int i = 0; i < 4; ++i) {
        int k = k0 + kq * 4 + i;
        int cg = c0base + c0 + ci;
        float v = 0.f;
        if (k < Kact && cg < Ctot) {
            v = X[(size_t)k * Ctot + cg] * cconst;
            if (ks) v *= ks[k];
            if (ns) v *= ns[cg];
        }
        tile[kq * 4 + i][ci] = v;
    }
    __syncthreads();
    // thread (cl, kq) emits 4 consecutive k for one output row c -> ushort4 stores
    int cl = threadIdx.x & 31, kq2 = threadIdx.x >> 5;
    us4 b0v, b1v;
#pragma unroll
    for (int i = 0; i < 4; ++i) {
        float v = tile[kq2 * 4 + i][cl];
        unsigned short b0 = f2h(v);
        b0v[i] = b0;
        b1v[i] = f2h(v - h2f(b0));
    }
    unsigned short* o = out + (size_t)(c0 + cl) * ld + (k0 + kq2 * 4);
    *(us4*)&o[0] = b0v;
    if (NS >= 2) *(us4*)&o[Kp] = b1v;
}

// ---------------- MFMA split-GEMM (XOR-swizzled LDS, conflict-free) ----------------
// Asymmetric splits: A has SA f16 splits, B has SB. Products with i+j<2 only.
// 2-phase double-buffered pipeline when LDS fits (SA+SB<=3): issue next tile's
// global_load_lds BEFORE computing the current tile, one barrier per tile ->
// load latency hides under ds_read+MFMA (latency-bound regime fix).
template <int SA, int SB, int EPI>
__global__ __launch_bounds__(256) void gemm_bt_k(
    const unsigned short* __restrict__ A, int ldA,
    const unsigned short* __restrict__ B, int ldB,
    int Kp, int ktot, int splits,
    float* __restrict__ Cpart,
    float* __restrict__ dst, int ldc, int coloff,
    int M, int N, float osc) {
    constexpr int NB = (SA + SB <= 3) ? 2 : 1;
    __shared__ __align__(16) short As[NB][SA][128 * 32];
    __shared__ __align__(16) short Bs[NB][SB][128 * 32];
    int tid = threadIdx.x;
    int lane = tid & 63, wid = tid >> 6;
    int wm = wid >> 1, wn = wid & 1;
    int bm = blockIdx.y * 128, bn = blockIdx.x * 128;
    int z = blockIdx.z;
    int kt0 = (int)((long long)ktot * z / splits);
    int kt1 = (int)((long long)ktot * (z + 1) / splits);
    int r_i = lane & 15, quad = lane >> 4;
    int sw = (quad ^ ((r_i >> 1) & 3)) << 3;
    f32x4 acc[4][4] = {};

    auto stage = [&](int t, int b) {
        int kbase = t * 32;
#pragma unroll
        for (int s = 0; s < SA; ++s)
#pragma unroll
            for (int it = 0; it < 2; ++it) {
                int flat = (it * 256 + tid) * 8;
                int row = flat >> 5;
                int blk = (flat >> 3) & 3;
                int ko = ((blk ^ ((row >> 1) & 3)) << 3);
                ld_lds16(A + (size_t)(bm + row) * ldA + s * Kp + kbase + ko, &As[b][s][flat]);
            }
#pragma unroll
        for (int s = 0; s < SB; ++s)
#pragma unroll
            for (int it = 0; it < 2; ++it) {
                int flat = (it * 256 + tid) * 8;
                int row = flat >> 5;
                int blk = (flat >> 3) & 3;
                int ko = ((blk ^ ((row >> 1) & 3)) << 3);
                ld_lds16(B + (size_t)(bn + row) * ldB + s * Kp + kbase + ko, &Bs[b][s][flat]);
            }
    };

    auto compute = [&](int b) {
        half8 af[SA][4], bfr[SB][4];
#pragma unroll
        for (int s = 0; s < SA; ++s)
#pragma unroll
            for (int mi = 0; mi < 4; ++mi)
                af[s][mi] = *(const half8*)&As[b][s][(wm * 64 + mi * 16 + r_i) * 32 + sw];
#pragma unroll
        for (int s = 0; s < SB; ++s)
#pragma unroll
            for (int mi = 0; mi < 4; ++mi)
                bfr[s][mi] = *(const half8*)&Bs[b][s][(wn * 64 + mi * 16 + r_i) * 32 + sw];
#pragma unroll
        for (int i = 0; i < SA; ++i)
#pragma unroll
            for (int j = 0; j < SB; ++j) {
                if (i + j >= 2) continue;
#pragma unroll
                for (int mi = 0; mi < 4; ++mi)
#pragma unroll
                    for (int ni = 0; ni < 4; ++ni)
                        acc[mi][ni] = __builtin_amdgcn_mfma_f32_16x16x32_f16(
                            af[i][mi], bfr[j][ni], acc[mi][ni], 0, 0, 0);
            }
    };

    if (NB == 2) {
        stage(kt0, 0);
        __syncthreads();
        int cur = 0;
        for (int t = kt0; t < kt1; ++t) {
            if (t + 1 < kt1) stage(t + 1, cur ^ 1);
            compute(cur);
            __syncthreads();   // drains next-tile loads; protects LDS reuse
            cur ^= 1;
        }
    } else {
        for (int t = kt0; t < kt1; ++t) {
            stage(t, 0);
            __syncthreads();
            compute(0);
            __syncthreads();
        }
    }

#pragma unroll
    for (int mi = 0; mi < 4; ++mi)
#pragma unroll
        for (int ni = 0; ni < 4; ++ni)
#pragma unroll
            for (int r = 0; r < 4; ++r) {
                int gm = bm + wm * 64 + mi * 16 + quad * 4 + r;
                int gn = bn + wn * 64 + ni * 16 + r_i;
                if (gm >= M || gn >= N) continue;
                float v = acc[mi][ni][r];
                if (splits > 1) {
                    Cpart[((size_t)z * M + gm) * N + gn] = v;  // raw; osc in epi_k
                } else {
                    v *= osc;
                    if (EPI == ERELU) v = fmaxf(v, 0.f);
                    else if (EPI == ESIG) v = 1.f / (1.f + expf(-v));
                    dst[(size_t)gm * ldc + coloff + gn] = v;
                }
            }
}

template <int EPI>
__global__ void epi_k(const float* __restrict__ Cpart, int splits, int M, int N,
                      float* __restrict__ dst, int ldc, int coloff, float osc) {
    int idx = blockIdx.x * 256 + threadIdx.x;
    if (idx >= M * N) return;
    size_t stride = (size_t)M * N;
    float v = 0.f;
    for (int s = 0; s < splits; ++s) v += Cpart[s * stride + idx];
    v *= osc;
    int m = idx / N, n = idx - m * N;
    if (EPI == ERELU) v = fmaxf(v, 0.f);
    else if (EPI == ESIG) v = 1.f / (1.f + expf(-v));
    dst[(size_t)m * ldc + coloff + n] = v;
}

// ---------------- host-side GEMM helpers ----------------
static inline int pick_splits(int nt, int mt, int Ma, int N, int ktiles, size_t cpn) {
    int tiles = nt * mt;
    if (tiles >= 256) return 1;
    int cap = (int)(cpn / ((size_t)Ma * N));
    int s = cdiv(768, tiles);                  // target ~3 blocks/CU
    if (s > cap) s = cap;
    if (s > ktiles) s = ktiles;
    if (s > 16) s = 16;
    if (s < 1) s = 1;
    return s;
}

template <int SA, int SB, int EPI>
static void gemm_packedA(hipStream_t s, const unsigned short* Ap, int ldA,
                         int M, int Kp, const unsigned short* Bp, int ldB, int N,
                         float* Cpart, size_t cpn, float* dst, int ldc, int coloff,
                         float osc) {
    int Ma = cdiv(M, 128) * 128;
    int ktiles = Kp / 32;
    int splits = pick_splits(cdiv(N, 128), Ma / 128, Ma, N, ktiles, cpn);
    dim3 g(cdiv(N, 128), Ma / 128, splits);
    if (splits == 1) {
        gemm_bt_k<SA, SB, EPI><<<g, 256, 0, s>>>(Ap, ldA, Bp, ldB, Kp, ktiles, 1, nullptr,
                                                 dst, ldc, coloff, M, N, osc);
    } else {
        gemm_bt_k<SA, SB, EPI><<<g, 256, 0, s>>>(Ap, ldA, Bp, ldB, Kp, ktiles, splits, Cpart,
                                                 nullptr, 0, 0, M, N, osc);
        epi_k<EPI><<<cdiv(M * N, 256), 256, 0, s>>>(Cpart, splits, M, N, dst, ldc, coloff, osc);
    }
}

template <int SA, int SB, int EPI>
static void gemm_rowsA(hipStream_t s,
                       const float* Asrc, int Mtot, int Kact, int Kp,
                       const float* rsc, const float* csc, float cscA,
                       unsigned short* PA, size_t PAelems,
                       const unsigned short* Bp, int ldB, int N,
                       float* Cpart, size_t cpn, float* dst, int ldc, int coloff,
                       float osc) {
    int ldA = SA * Kp;
    int maxCM = (int)((PAelems / (size_t)ldA) / 128) * 128;
    if (maxCM < 128) maxCM = 128;
    int ktiles = Kp / 32;
    for (int r0 = 0; r0 < Mtot; r0 += maxCM) {
        int Mv = (Mtot - r0 < maxCM) ? (Mtot - r0) : maxCM;
        int Ma = cdiv(Mv, 128) * 128;
        pack_rows_k<<<Ma, 256, 0, s>>>(Asrc, Mtot, Kact, r0, Kp, SA, ldA, rsc, csc, cscA, PA);
        int splits = pick_splits(cdiv(N, 128), Ma / 128, Ma, N, ktiles, cpn);
        dim3 g(cdiv(N, 128), Ma / 128, splits);
        if (splits == 1) {
            gemm_bt_k<SA, SB, EPI><<<g, 256, 0, s>>>(PA, ldA, Bp, ldB, Kp, ktiles, 1, nullptr,
                                                     dst + (size_t)r0 * ldc, ldc, coloff, Mv, N, osc);
        } else {
            gemm_bt_k<SA, SB, EPI><<<g, 256, 0, s>>>(PA, ldA, Bp, ldB, Kp, ktiles, splits, Cpart,
                                                     nullptr, 0, 0, Mv, N, osc);
            epi_k<EPI><<<cdiv(Mv * N, 256), 256, 0, s>>>(Cpart, splits, Mv, N,
                                                         dst + (size_t)r0 * ldc, ldc, coloff, osc);
        }
    }
}

template <int SA, int SB, int EPI>
static void gemm_transA(hipStream_t s,
                        const float* Asrc, int Mtot, int Kact, int Kp,
                        const float* ks, const float* ns, float cscA,
                        unsigned short* PA, size_t PAelems,
                        const unsigned short* Bp, int ldB, int N,
                        float* Cpart, size_t cpn, float* dst, int ldc, int coloff,
                        float osc) {
    int ldA = SA * Kp;
    int maxCM = (int)((PAelems / (size_t)ldA) / 128) * 128;
    if (maxCM < 128) maxCM = 128;
    int ktiles = Kp / 32;
    for (int r0 = 0; r0 < Mtot; r0 += maxCM) {
        int Mv = (Mtot - r0 < maxCM) ? (Mtot - r0) : maxCM;
        int Ma = cdiv(Mv, 128) * 128;
        pack_trans_k<<<dim3(Ma / 32, ktiles), 256, 0, s>>>(Asrc, Kact, Mtot, r0, Kp, SA, ldA,
                                                           ks, ns, cscA, PA);
        int splits = pick_splits(cdiv(N, 128), Ma / 128, Ma, N, ktiles, cpn);
        dim3 g(cdiv(N, 128), Ma / 128, splits);
        if (splits == 1) {
            gemm_bt_k<SA, SB, EPI><<<g, 256, 0, s>>>(PA, ldA, Bp, ldB, Kp, ktiles, 1, nullptr,
                                                     dst + (size_t)r0 * ldc, ldc, coloff, Mv, N, osc);
        } else {
            gemm_bt_k<SA, SB, EPI><<<g, 256, 0, s>>>(PA, ldA, Bp, ldB, Kp, ktiles, splits, Cpart,
                                                     nullptr, 0, 0, Mv, N, osc);
            epi_k<EPI><<<cdiv(Mv * N, 256), 256, 0, s>>>(Cpart, splits, Mv, N,
                                                         dst + (size_t)r0 * ldc, ldc, coloff, osc);
        }
    }
}

// ---------------- fallback fp32 SGEMM (round-1 proven path) ----------------
#define BM 64
#define BN 64
#define BK 16

template <bool TA, bool TB, int EPI>
__global__ __launch_bounds__(256) void gemm_f32_k(
    int M, int N, int K,
    const float* __restrict__ A, int lda,
    const float* __restrict__ B, int ldb,
    float* __restrict__ C, int ldc,
    const float* __restrict__ scaleB,
    const float* __restrict__ scaleC) {
    __shared__ float Asf[BK][BM + 4];
    __shared__ float Bsf[BK][BN + 4];
    int bn = blockIdx.x * BN;
    int bm = blockIdx.y * BM;
    int tid = threadIdx.x;
    int tx = tid & 15;
    int ty = tid >> 4;
    float acc[4][4] = {};
    for (int t = 0; t < K; t += BK) {
#pragma unroll
        for (int it = 0; it < (BM * BK) / 256; ++it) {
            int l = tid + it * 256;
            int k, m;
            if (TA) { k = l / BM; m = l % BM; }
            else    { m = l / BK; k = l % BK; }
            int gm = bm + m, gk = t + k;
            float v = 0.f;
            if (gm < M && gk < K)
                v = TA ? A[(size_t)gk * lda + gm] : A[(size_t)gm * lda + gk];
            Asf[k][m] = v;
        }
#pragma unroll
        for (int it = 0; it < (BN * BK) / 256; ++it) {
            int l = tid + it * 256;
            int k, n;
            if (TB) { n = l / BK; k = l % BK; }
            else    { k = l / BN; n = l % BN; }
            int gn = bn + n, gk = t + k;
            float v = 0.f;
            if (gn < N && gk < K) {
                v = TB ? B[(size_t)gn * ldb + gk] : B[(size_t)gk * ldb + gn];
                if (scaleB) v *= scaleB[gk];
            }
            Bsf[k][n] = v;
        }
        __syncthreads();
#pragma unroll
        for (int kk = 0; kk < BK; ++kk) {
            float a[4], b[4];
#pragma unroll
            for (int i = 0; i < 4; ++i) a[i] = Asf[kk][ty * 4 + i];
#pragma unroll
            for (int j = 0; j < 4; ++j) b[j] = Bsf[kk][tx * 4 + j];
#pragma unroll
            for (int i = 0; i < 4; ++i)
#pragma unroll
                for (int j = 0; j < 4; ++j)
                    acc[i][j] = fmaf(a[i], b[j], acc[i][j]);
        }
        __syncthreads();
    }
#pragma unroll
    for (int i = 0; i < 4; ++i) {
        int gm = bm + ty * 4 + i;
        if (gm >= M) continue;
#pragma unroll
        for (int j = 0; j < 4; ++j) {
            int gn = bn + tx * 4 + j;
            if (gn >= N) continue;
            float v = acc[i][j];
            if (EPI == ERELUSC) v = fmaxf(scaleC[gm] * v, 0.f);
            else if (EPI == ERELU) v = fmaxf(v, 0.f);
            else if (EPI == ESIG) v = 1.f / (1.f + expf(-v));
            C[(size_t)gm * ldc + gn] = v;
        }
    }
}

template <bool TA, bool TB, int EPI>
static inline void launch_gemm_f32(int M, int N, int K,
                                   const float* A, int lda,
                                   const float* B, int ldb,
                                   float* C, int ldc,
                                   const float* sB, const float* sC,
                                   hipStream_t stream) {
    dim3 grid((N + BN - 1) / BN, (M + BM - 1) / BM);
    gemm_f32_k<TA, TB, EPI><<<grid, dim3(256), 0, stream>>>(M, N, K, A, lda, B, ldb, C, ldc, sB, sC);
}

static void run_fp32_path(void* const* d_in, void* d_out, void* d_ws, hipStream_t stream) {
    const float* R   = (const float*)d_in[0];
    const float* D   = (const float*)d_in[1];
    const float* T   = (const float*)d_in[2];
    const float* H_d = (const float*)d_in[3];
    const float* H_t = (const float*)d_in[4];
    const float* W1g[2] = {(const float*)d_in[5], (const float*)d_in[7]};
    const float* W2g[2] = {(const float*)d_in[6], (const float*)d_in[8]};
    const float* Wd[3]  = {(const float*)d_in[9],  (const float*)d_in[11], (const float*)d_in[13]};
    const float* Wt[3]  = {(const float*)d_in[10], (const float*)d_in[12], (const float*)d_in[14]};
    float* out = (float*)d_out;
    float* ws = (float*)d_ws;
    size_t o = 0;
    auto alloc = [&](size_t n) { float* p = ws + o; o += n; return p; };
    float* sd   = alloc(DNUM);
    float* st   = alloc(TNUM);
    float* rdR  = alloc(DNUM);
    float* rtR  = alloc(TNUM);
    float* rd   = alloc(DNUM);
    float* rt   = alloc(TNUM);
    float* hd1  = alloc((size_t)DNUM * UNITS);
    float* ht1  = alloc((size_t)TNUM * UNITS);
    float* hd2  = alloc((size_t)DNUM * UNITS);
    float* ht2  = alloc((size_t)TNUM * UNITS);
    float* GHd  = alloc((size_t)DNUM * UNITS);
    float* GHt  = alloc((size_t)TNUM * UNITS);
    float* tv   = alloc((size_t)DNUM * TOPK);
    int*   ti   = (int*)alloc((size_t)DNUM * TOPK);
    float* accT = alloc((size_t)TNUM * FEAT);
    float* Cd   = alloc((size_t)DNUM * 3 * FEAT);
    float* Ct   = alloc((size_t)TNUM * 3 * FEAT);

    rowsum_rsqrt_k<<<DNUM, 256, 0, stream>>>(D, DNUM, sd);
    rowsum_rsqrt_k<<<TNUM, 256, 0, stream>>>(T, TNUM, st);
    rowsum_rsqrt_k<<<DNUM, 256, 0, stream>>>(R, TNUM, rdR);
    fill_zero_k<<<cdiv(TNUM, 256), 256, 0, stream>>>(rtR, TNUM);
    colsum_partial_k<<<dim3(cdiv(TNUM, 256), 32), 256, 0, stream>>>(R, DNUM, TNUM, rtR);
    rsqrt_safe_k<<<cdiv(TNUM, 256), 256, 0, stream>>>(rtR, TNUM);

    const float* hd_in = H_d;
    const float* ht_in = H_t;
    for (int l = 0; l < 2; ++l) {
        int F = (l == 0) ? FEAT : UNITS;
        int ld3 = 3 * F;
        launch_gemm_f32<false, false, ENONE>(DNUM, UNITS, F, hd_in, F, W1g[l], UNITS, GHd, UNITS, nullptr, nullptr, stream);
        launch_gemm_f32<false, false, ENONE>(TNUM, UNITS, F, ht_in, F, W2g[l], UNITS, GHt, UNITS, nullptr, nullptr, stream);
        launch_gemm_f32<false, true, ESIG>(DNUM, TNUM, UNITS, GHd, UNITS, GHt, UNITS, out, TNUM, nullptr, nullptr, stream);
        topk_k<<<DNUM, 256, 0, stream>>>(out, TNUM, tv, ti, rd);
        fill_zero_k<<<cdiv(TNUM, 256), 256, 0, stream>>>(rt, TNUM);
        scatter_colsum_k<<<cdiv(DNUM * TOPK, 256), 256, 0, stream>>>(tv, ti, rt, DNUM * TOPK);
        rsqrt_safe_k<<<cdiv(TNUM, 256), 256, 0, stream>>>(rt, TNUM);
        gather_hdt_k<<<DNUM, 256, 0, stream>>>(tv, ti, rt, rd, ht_in, F, Cd, ld3, F);
        fill_zero_k<<<cdiv(TNUM * F, 256), 256, 0, stream>>>(accT, TNUM * F);
        scatter_htd_k<<<DNUM, 256, 0, stream>>>(tv, ti, rd, hd_in, F, accT);
        finalize_htd_k<<<TNUM, 256, 0, stream>>>(accT, rt, F, Ct, ld3, F);
        copy_rows_k<<<DNUM, 256, 0, stream>>>(hd_in, F, Cd, ld3);
        copy_rows_k<<<TNUM, 256, 0, stream>>>(ht_in, F, Ct, ld3);
        launch_gemm_f32<false, false, ERELUSC>(DNUM, F, DNUM, D, DNUM, hd_in, F, Cd + 2 * F, ld3, sd, sd, stream);
        launch_gemm_f32<false, false, ERELUSC>(TNUM, F, TNUM, T, TNUM, ht_in, F, Ct + 2 * F, ld3, st, st, stream);
        float* hdo = (l == 0) ? hd1 : hd2;
        float* hto = (l == 0) ? ht1 : ht2;
        launch_gemm_f32<false, false, ERELU>(DNUM, UNITS, 3 * F, Cd, ld3, Wd[l], UNITS, hdo, UNITS, nullptr, nullptr, stream);
        launch_gemm_f32<false, false, ERELU>(TNUM, UNITS, 3 * F, Ct, ld3, Wt[l], UNITS, hto, UNITS, nullptr, nullptr, stream);
        hd_in = hdo;
        ht_in = hto;
    }
    {
        int F = UNITS, ld3 = 3 * UNITS;
        launch_gemm_f32<false, false, ERELUSC>(DNUM, F, TNUM, R, TNUM, ht_in, F, Cd + F, ld3, rtR, rdR, stream);
        launch_gemm_f32<true, false, ERELUSC>(TNUM, F, DNUM, R, TNUM, hd_in, F, Ct + F, ld3, rdR, rtR, stream);
        copy_rows_k<<<DNUM, 256, 0, stream>>>(hd_in, F, Cd, ld3);
        copy_rows_k<<<TNUM, 256, 0, stream>>>(ht_in, F, Ct, ld3);
        launch_gemm_f32<false, false, ERELUSC>(DNUM, F, DNUM, D, DNUM, hd_in, F, Cd + 2 * F, ld3, sd, sd, stream);
        launch_gemm_f32<false, false, ERELUSC>(TNUM, F, TNUM, T, TNUM, ht_in, F, Ct + 2 * F, ld3, st, st, stream);
        launch_gemm_f32<false, false, ERELU>(DNUM, UNITS, 3 * F, Cd, ld3, Wd[2], UNITS, hd1, UNITS, nullptr, nullptr, stream);
        launch_gemm_f32<false, false, ERELU>(TNUM, UNITS, 3 * F, Ct, ld3, Wt[2], UNITS, ht1, UNITS, nullptr, nullptr, stream);
        launch_gemm_f32<false, true, ESIG>(DNUM, TNUM, UNITS, hd1, UNITS, ht1, UNITS, out, TNUM, nullptr, nullptr, stream);
    }
}

// ---------------- main driver ----------------
extern "C" void kernel_launch(void* const* d_in, const int* in_sizes, int n_in,
                              void* d_out, int out_size, void* d_ws, size_t ws_size,
                              hipStream_t stream) {
    (void)in_sizes; (void)n_in; (void)out_size;
    const float* R   = (const float*)d_in[0];
    const float* D   = (const float*)d_in[1];
    const float* T   = (const float*)d_in[2];
    const float* H_d = (const float*)d_in[3];
    const float* H_t = (const float*)d_in[4];
    const float* W1g[2] = {(const float*)d_in[5], (const float*)d_in[7]};
    const float* W2g[2] = {(const float*)d_in[6], (const float*)d_in[8]};
    const float* Wd[3]  = {(const float*)d_in[9],  (const float*)d_in[11], (const float*)d_in[13]};
    const float* Wt[3]  = {(const float*)d_in[10], (const float*)d_in[12], (const float*)d_in[14]};
    float* out = (float*)d_out;   // [4000,2000]; doubles as GL score scratch

    const int KpD = 4000, KpT = 2016, KpU = 224;
    const int KpF0 = 256;
    const int Kp3F0 = 768, Kp3F1 = 608;

    // f16-split range scales (exact powers of two; undone by osc in epilogue)
    const float SH = 16.f;     // feature matrices (H, GH, Cd, hd1...)  |v| <~ 30
    const float SW = 64.f;     // glorot weights                        |v| <~ 0.12
    const float SG = 2048.f;   // norm-scaled graphs D-hat/T-hat/R-hat  |v| <~ 1e-3..1
    const float OHW = 1.f / (16.f * 64.f);
    const float OHH = 1.f / (16.f * 16.f);
    const float OGH = 1.f / (2048.f * 16.f);

    char* base = (char*)d_ws;
    size_t off = 0;
    auto alloc = [&](size_t bytes) -> void* {
        off = (off + 255) & ~(size_t)255;
        void* p = base + off;
        off += bytes;
        return p;
    };
    float* sd   = (float*)alloc(DNUM * 4);
    float* st   = (float*)alloc(TNUM * 4);
    float* rdR  = (float*)alloc(DNUM * 4);
    float* rtR  = (float*)alloc(TNUM * 4);
    float* rdv  = (float*)alloc(DNUM * 4);
    float* rt   = (float*)alloc(TNUM * 4);
    float* hd1  = (float*)alloc((size_t)DNUM * UNITS * 4);
    float* ht1  = (float*)alloc((size_t)TNUM * UNITS * 4);
    float* hd2  = (float*)alloc((size_t)DNUM * UNITS * 4);
    float* ht2  = (float*)alloc((size_t)TNUM * UNITS * 4);
    float* GHd  = (float*)alloc((size_t)DNUM * UNITS * 4);
    float* GHt  = (float*)alloc((size_t)TNUM * UNITS * 4);
    float* tv   = (float*)alloc((size_t)DNUM * TOPK * 4);
    int*   ti   = (int*)alloc((size_t)DNUM * TOPK * 4);
    float* accT = (float*)alloc((size_t)TNUM * FEAT * 4);
    float* Cd   = (float*)alloc((size_t)DNUM * 3 * FEAT * 4);
    float* Ct   = (float*)alloc((size_t)TNUM * 3 * FEAT * 4);
    unsigned short* PB = (unsigned short*)alloc((size_t)3200000 * 2);  // B packs

    // ---- tiered workspace plan (1-split A packs for graphs, 2-split B) ----
    const size_t PA_DYN = (size_t)4096 * 4032 * 2;    // 33.0 MB dynamic A packs
    const size_t DP_B   = (size_t)4096 * 4000 * 2;    // persistent 1-split D-hat
    const size_t TP_B   = (size_t)2048 * 2016 * 2;    // persistent 1-split T-hat
    const size_t RP_B   = (size_t)2048 * 4000 * 2;    // persistent dense 1-split R-filter
    const size_t CP_MIN = (size_t)8 * 1024 * 1024 * 4;
    bool persist = false;
    unsigned short *Dp = nullptr, *Tp = nullptr, *Rp = nullptr, *PA = nullptr;
    float* Cpart = nullptr;
    size_t cpn = 0, PAelems = 0;
    {
        size_t aligned_off = (off + 255) & ~(size_t)255;
        if (ws_size >= aligned_off + PA_DYN + DP_B + TP_B + RP_B + CP_MIN + 1024) {
            persist = true;
            PA = (unsigned short*)alloc(PA_DYN);  PAelems = PA_DYN / 2;
            Dp = (unsigned short*)alloc(DP_B);
            Tp = (unsigned short*)alloc(TP_B);
            Rp = (unsigned short*)alloc(RP_B);
            off = (off + 255) & ~(size_t)255;
            size_t cb = ws_size - off;
            if (cb > (size_t)64 * 1024 * 1024 * 4) cb = (size_t)64 * 1024 * 1024 * 4;
            Cpart = (float*)(base + off);
            cpn = cb / 4;
        } else {
            // fallback: shared PA, fixed Cpart, legacy scatter H_td
            const size_t PA_FULL = (size_t)4096 * 8000 * 2;
            const size_t PA_MINB = (size_t)1024 * 8000 * 2;
            const size_t CP_BIG = (size_t)8 * 1024 * 1024 * 4;
            const size_t CP_SML = (size_t)4 * 1024 * 1024 * 4;
            size_t rem = (ws_size > aligned_off) ? ws_size - aligned_off : 0;
            size_t cpart_bytes;
            if (rem >= PA_FULL + CP_BIG + 512)      cpart_bytes = CP_BIG;
            else if (rem >= PA_FULL + CP_SML + 512) cpart_bytes = CP_SML;
            else if (rem >= PA_MINB + CP_SML + 512) cpart_bytes = CP_SML;
            else { run_fp32_path(d_in, d_out, d_ws, stream); return; }
            Cpart = (float*)alloc(cpart_bytes);
            cpn = cpart_bytes / 4;
            off = (off + 255) & ~(size_t)255;
            PA = (unsigned short*)(base + off);
            PAelems = (ws_size - off) / 2;
        }
    }

    // ---- norm vectors ----
    rowsum_rsqrt_k<<<DNUM, 256, 0, stream>>>(D, DNUM, sd);
    rowsum_rsqrt_k<<<TNUM, 256, 0, stream>>>(T, TNUM, st);
    rowsum_rsqrt_k<<<DNUM, 256, 0, stream>>>(R, TNUM, rdR);
    fill_zero_k<<<cdiv(TNUM, 256), 256, 0, stream>>>(rtR, TNUM);
    colsum_partial_k<<<dim3(cdiv(TNUM, 256), 32), 256, 0, stream>>>(R, DNUM, TNUM, rtR);
    rsqrt_safe_k<<<cdiv(TNUM, 256), 256, 0, stream>>>(rtR, TNUM);

    // ---- persistent packs: D-hat & T-hat once (1-split); zero R-filter ----
    if (persist) {
        pack_rows_k<<<4096, 256, 0, stream>>>(D, DNUM, DNUM, 0, KpD, 1, KpD, sd, sd, SG, Dp);
        pack_rows_k<<<2048, 256, 0, stream>>>(T, TNUM, TNUM, 0, KpT, 1, KpT, st, st, SG, Tp);
        fill_zero_k<<<cdiv((int)(RP_B / 4), 256), 256, 0, stream>>>((float*)Rp, (int)(RP_B / 4));
    }

    const float* hd_in = H_d;
    const float* ht_in = H_t;
    for (int l = 0; l < 2; ++l) {
        int F = (l == 0) ? FEAT : UNITS;
        int KpF = (l == 0) ? KpF0 : KpU;
        int Kp3 = (l == 0) ? Kp3F0 : Kp3F1;
        int ld3 = 3 * F;
        // ---- GL scoring (full 2x2-split: keeps top-k stable) ----
        pack_trans_k<<<dim3(8, KpF / 32), 256, 0, stream>>>(W1g[l], F, UNITS, 0, KpF, 2, 2 * KpF, nullptr, nullptr, SW, PB);
        gemm_rowsA<2, 2, ENONE>(stream, hd_in, DNUM, F, KpF, nullptr, nullptr, SH, PA, PAelems,
                                PB, 2 * KpF, UNITS, Cpart, cpn, GHd, UNITS, 0, OHW);
        pack_trans_k<<<dim3(8, KpF / 32), 256, 0, stream>>>(W2g[l], F, UNITS, 0, KpF, 2, 2 * KpF, nullptr, nullptr, SW, PB);
        gemm_rowsA<2, 2, ENONE>(stream, ht_in, TNUM, F, KpF, nullptr, nullptr, SH, PA, PAelems,
                                PB, 2 * KpF, UNITS, Cpart, cpn, GHt, UNITS, 0, OHW);
        pack_rows_k<<<2048, 256, 0, stream>>>(GHt, TNUM, UNITS, 0, KpU, 2, 2 * KpU, nullptr, nullptr, SH, PB);
        gemm_rowsA<2, 2, ESIG>(stream, GHd, DNUM, UNITS, KpU, nullptr, nullptr, SH, PA, PAelems,
                               PB, 2 * KpU, TNUM, Cpart, cpn, out, TNUM, 0, OHH);
        // ---- top-k + sparse CGC terms ----
        topk_wave_k<<<DNUM / 4, 256, 0, stream>>>(out, TNUM, tv, ti, rdv);
        fill_zero_k<<<cdiv(TNUM, 256), 256, 0, stream>>>(rt, TNUM);
        colsum_lds_k<<<cdiv(DNUM * TOPK, CS_ENT), 256, 0, stream>>>(tv, ti, rt, DNUM * TOPK);
        rsqrt_safe_k<<<cdiv(TNUM, 256), 256, 0, stream>>>(rt, TNUM);
        gather_hdt_k<<<DNUM, 256, 0, stream>>>(tv, ti, rt, rdv, ht_in, F, Cd, ld3, F);
        copy_rows_k<<<DNUM, 256, 0, stream>>>(hd_in, F, Cd, ld3);
        copy_rows_k<<<TNUM, 256, 0, stream>>>(ht_in, F, Ct, ld3);
        // ---- dense graph convs + H_td (1-split graph A x 2-split hd B) ----
        pack_trans_k<<<dim3(8, KpD / 32), 256, 0, stream>>>(hd_in, DNUM, F, 0, KpD, 2, 2 * KpD, nullptr, nullptr, SH, PB);
        if (persist) {
            place_rp_k<<<cdiv(DNUM * TOPK, 256), 256, 0, stream>>>(tv, ti, rdv, rt, KpD, SG, Rp);
            gemm_packedA<1, 2, ERELU>(stream, Rp, KpD, TNUM, KpD, PB, 2 * KpD, F, Cpart, cpn, Ct, ld3, F, OGH);
            gemm_packedA<1, 2, ERELU>(stream, Dp, KpD, DNUM, KpD, PB, 2 * KpD, F, Cpart, cpn, Cd, ld3, 2 * F, OGH);
            zero_rp_k<<<cdiv(DNUM * TOPK, 256), 256, 0, stream>>>(ti, KpD, Rp);
        } else {
            fill_zero_k<<<cdiv(TNUM * F, 256), 256, 0, stream>>>(accT, TNUM * F);
            scatter_htd_k<<<DNUM, 256, 0, stream>>>(tv, ti, rdv, hd_in, F, accT);
            finalize_htd_k<<<TNUM, 256, 0, stream>>>(accT, rt, F, Ct, ld3, F);
            gemm_rowsA<1, 2, ERELU>(stream, D, DNUM, DNUM, KpD, sd, sd, SG, PA, PAelems,
                                    PB, 2 * KpD, F, Cpart, cpn, Cd, ld3, 2 * F, OGH);
        }
        pack_trans_k<<<dim3(8, KpT / 32), 256, 0, stream>>>(ht_in, TNUM, F, 0, KpT, 2, 2 * KpT, nullptr, nullptr, SH, PB);
        if (persist)
            gemm_packedA<1, 2, ERELU>(stream, Tp, KpT, TNUM, KpT, PB, 2 * KpT, F, Cpart, cpn, Ct, ld3, 2 * F, OGH);
        else
            gemm_rowsA<1, 2, ERELU>(stream, T, TNUM, TNUM, KpT, st, st, SG, PA, PAelems,
                                    PB, 2 * KpT, F, Cpart, cpn, Ct, ld3, 2 * F, OGH);
        pack_trans_k<<<dim3(8, Kp3 / 32), 256, 0, stream>>>(Wd[l], 3 * F, UNITS, 0, Kp3, 2, 2 * Kp3, nullptr, nullptr, SW, PB);
        float* hdo = (l == 0) ? hd1 : hd2;
        gemm_rowsA<2, 2, ERELU>(stream, Cd, DNUM, 3 * F, Kp3, nullptr, nullptr, SH, PA, PAelems,
                                PB, 2 * Kp3, UNITS, Cpart, cpn, hdo, UNITS, 0, OHW);
        pack_trans_k<<<dim3(8, Kp3 / 32), 256, 0, stream>>>(Wt[l], 3 * F, UNITS, 0, Kp3, 2, 2 * Kp3, nullptr, nullptr, SW, PB);
        float* hto = (l == 0) ? ht1 : ht2;
        gemm_rowsA<2, 2, ERELU>(stream, Ct, TNUM, 3 * F, Kp3, nullptr, nullptr, SH, PA, PAelems,
                                PB, 2 * Kp3, UNITS, Cpart, cpn, hto, UNITS, 0, OHW);
        hd_in = hdo;
        ht_in = hto;
    }

    // ---- output CGC on original dense graphs ----
    {
        int F = UNITS, ld3 = 3 * UNITS, Kp3 = Kp3F1;
        pack_trans_k<<<dim3(8, KpT / 32), 256, 0, stream>>>(ht_in, TNUM, F, 0, KpT, 2, 2 * KpT, nullptr, nullptr, SH, PB);
        gemm_rowsA<1, 2, ERELU>(stream, R, DNUM, TNUM, KpT, rdR, rtR, SG, PA, PAelems,
                                PB, 2 * KpT, F, Cpart, cpn, Cd, ld3, F, OGH);
        pack_trans_k<<<dim3(8, KpD / 32), 256, 0, stream>>>(hd_in, DNUM, F, 0, KpD, 2, 2 * KpD, nullptr, nullptr, SH, PB);
        gemm_transA<1, 2, ERELU>(stream, R, TNUM, DNUM, KpD, rdR, rtR, SG, PA, PAelems,
                                 PB, 2 * KpD, F, Cpart, cpn, Ct, ld3, F, OGH);
        copy_rows_k<<<DNUM, 256, 0, stream>>>(hd_in, F, Cd, ld3);
        copy_rows_k<<<TNUM, 256, 0, stream>>>(ht_in, F, Ct, ld3);
        // H_dd: PB still holds the 2-split hd pack (ld 2*KpD)
        if (persist)
            gemm_packedA<1, 2, ERELU>(stream, Dp, KpD, DNUM, KpD, PB, 2 * KpD, F, Cpart, cpn, Cd, ld3, 2 * F, OGH);
        else
            gemm_rowsA<1, 2, ERELU>(stream, D, DNUM, DNUM, KpD, sd, sd, SG, PA, PAelems,
                                    PB, 2 * KpD, F, Cpart, cpn, Cd, ld3, 2 * F, OGH);
        pack_trans_k<<<dim3(8, KpT / 32), 256, 0, stream>>>(ht_in, TNUM, F, 0, KpT, 2, 2 * KpT, nullptr, nullptr, SH, PB);
        if (persist)
            gemm_packedA<1, 2, ERELU>(stream, Tp, KpT, TNUM, KpT, PB, 2 * KpT, F, Cpart, cpn, Ct, ld3, 2 * F, OGH);
        else
            gemm_rowsA<1, 2, ERELU>(stream, T, TNUM, TNUM, KpT, st, st, SG, PA, PAelems,
                                    PB, 2 * KpT, F, Cpart, cpn, Ct, ld3, 2 * F, OGH);
        pack_trans_k<<<dim3(8, Kp3 / 32), 256, 0, stream>>>(Wd[2], 3 * F, UNITS, 0, Kp3, 2, 2 * Kp3, nullptr, nullptr, SW, PB);
        gemm_rowsA<2, 2, ERELU>(stream, Cd, DNUM, 3 * F, Kp3, nullptr, nullptr, SH, PA, PAelems,
                                PB, 2 * Kp3, UNITS, Cpart, cpn, hd1, UNITS, 0, OHW);
        pack_trans_k<<<dim3(8, Kp3 / 32), 256, 0, stream>>>(Wt[2], 3 * F, UNITS, 0, Kp3, 2, 2 * Kp3, nullptr, nullptr, SW, PB);
        gemm_rowsA<2, 2, ERELU>(stream, Ct, TNUM, 3 * F, Kp3, nullptr, nullptr, SH, PA, PAelems,
                                PB, 2 * Kp3, UNITS, Cpart, cpn, ht1, UNITS, 0, OHW);
        // R_pred = sigmoid(hd1 @ ht1^T)  (full 2x2-split: output precision)
        pack_rows_k<<<2048, 256, 0, stream>>>(ht1, TNUM, UNITS, 0, KpU, 2, 2 * KpU, nullptr, nullptr, SH, PB);
        gemm_rowsA<2, 2, ESIG>(stream, hd1, DNUM, UNITS, KpU, nullptr, nullptr, SH, PA, PAelems,
                               PB, 2 * KpU, TNUM, Cpart, cpn, out, TNUM, 0, OHH);
    }
}